// Round 6
// baseline (119.517 us; speedup 1.0000x reference)
//
#include <hip/hip_runtime.h>
#include <stdint.h>

#define BATCH 16
#define NPROP 16384
#define NGT   128
#define NSAMP 256
#define NFG   64
#define GCAP  512
#define PCAP  8192
#define NEGT  0x780002u   // neg high/low mant split; strict f32(2+r) separation (RNE)

typedef unsigned long long ull;

// ---------- threefry2x32 block (key 0,1) ----------
__device__ __forceinline__ void thr_block(uint32_t c0, uint32_t c1,
                                          uint32_t* o0, uint32_t* o1) {
    const uint32_t k0 = 0u, k1 = 1u, ks2 = 0x1BD11BDBu; // 0^1^0x1BD11BDA
    uint32_t x0 = c0 + k0, x1 = c1 + k1;
#define RND(d) { x0 += x1; x1 = (x1 << d) | (x1 >> (32 - d)); x1 ^= x0; }
    RND(13) RND(15) RND(26) RND(6)   x0 += k1;  x1 += ks2 + 1u;
    RND(17) RND(29) RND(16) RND(24)  x0 += ks2; x1 += k0 + 2u;
    RND(13) RND(15) RND(26) RND(6)   x0 += k0;  x1 += k1 + 3u;
    RND(17) RND(29) RND(16) RND(24)  x0 += k1;  x1 += ks2 + 4u;
    RND(13) RND(15) RND(26) RND(6)   x0 += ks2; x1 += k0 + 5u;
#undef RND
    *o0 = x0; *o1 = x1;
}

__device__ __forceinline__ uint32_t thr_part_xor(uint32_t f) {
    uint32_t a, b; thr_block(0u, f, &a, &b);
    return a ^ b;
}

// zero packed counters (16 batches x stride-8 ull) + barrier slots
__global__ void k_init(uint32_t* z) {
    if (threadIdx.x < 16 * 8 * 2 + 2) z[threadIdx.x] = 0u;
}

// list entry (u64): [44]=isPos, [43:21]=r mantissa (bits>>9), [20:7]=16383-n, [6:0]=argmax gt
// slabs per batch: 0=pos, 1=negHigh (mant>=NEGT), 2=negLow, 3=ignore (dense, atomic bases)
__global__ void __launch_bounds__(1024, 4) k_fused(
    const float* __restrict__ props, const float* __restrict__ gts,
    ull* __restrict__ lists, ull* __restrict__ cnts, uint32_t* __restrict__ bar,
    float* __restrict__ out)
{
#pragma clang fp contract(off)
    const int tid = threadIdx.x;
    const int bid = blockIdx.x;

    // phase-A shared
    __shared__ float2 sA[130];
    __shared__ float2 sB[130];
    __shared__ float  sag[130];
    __shared__ uint32_t wc[4][16], we_s[4][16];
    __shared__ ull sPack;
    // select-phase shared
    __shared__ ull      dpos[PCAP];      // 64 KB dense pos stage
    __shared__ uint32_t hist[2048];
    __shared__ ull      gat[GCAP];
    __shared__ ull      selk[NSAMP];
    __shared__ uint32_t sela[NSAMP];
    __shared__ uint32_t sh_dig, sh_k, sh_cnt_in, gcnt, selc;
    __shared__ ull sh_thr;

    // ================= phase A: IoU + label + 4-slab compaction =================
    {
        const int ab = bid >> 4;              // batch of this compute block
        const int half = tid & 1;             // 2 lanes per proposal: GTs 0-63 / 64-127
        if (tid < NGT) {
            float4 g = ((const float4*)gts)[(size_t)ab * NGT + tid];
            int idx = (tid < 64) ? tid : tid + 1;   // odd half at +65: disjoint banks
            sA[idx] = make_float2(g.x, g.y);
            sB[idx] = make_float2(g.z, g.w);
            sag[idx] = (g.z - g.x) * (g.w - g.y);
        }
        __syncthreads();
        const int base  = half ? 65 : 0;
        const int gbias = half ? 64 : 0;
        ull* slab = lists + (size_t)ab * 4 * NPROP;

        for (int cc = 0; cc < 2; ++cc) {
            const int seg = (bid & 15) * 2 + cc;      // 32 segs/batch, same batch both
            const int n = seg * 512 + (tid >> 1);
            const float4 pb = ((const float4*)props)[(size_t)ab * NPROP + n];
            const float ap = (pb.z - pb.x) * (pb.w - pb.y);
            float best = -1.0f; int bg = 0;
            #pragma unroll 4
            for (int i = 0; i < 64; ++i) {
                const float2 a = sA[base + i];
                const float2 c = sB[base + i];
                float w  = fmaxf(fminf(pb.z, c.x) - fmaxf(pb.x, a.x), 0.0f);
                float hh = fmaxf(fminf(pb.w, c.y) - fmaxf(pb.y, a.y), 0.0f);
                float inter = w * hh;
                float un = fmaxf(ap + sag[base + i] - inter, 1e-8f);
                float iou = inter / un;                 // IEEE f32 div = numpy bits
                if (iou > best) { best = iou; bg = gbias + i; }
            }
            // merge halves: even lane owns; strict > keeps half0 on float-ties
            float ob = __shfl_xor(best, 1);
            int  obg = __shfl_xor(bg, 1);
            if (half == 0 && ob > best) { best = ob; bg = obg; }

            uint32_t lab = (best >= 0.5f) ? 2u : ((best < 0.1f) ? 1u : 0u);
            const uint32_t f = (uint32_t)ab * NPROP + (uint32_t)n;
            uint32_t mant = thr_part_xor(f) >> 9;
            ull entry = ((ull)(lab == 2u) << 44) | ((ull)mant << 21)
                      | ((ull)(16383u - (uint32_t)n) << 7) | (ull)(uint32_t)bg;

            const bool isEven = (half == 0);
            bool cP = isEven && (lab == 2u);
            bool cH = isEven && (lab == 1u) && (mant >= NEGT);
            bool cL = isEven && (lab == 1u) && (mant <  NEGT);
            bool cI = isEven && (lab == 0u);
            ull mP = __ballot(cP), mH = __ballot(cH), mL = __ballot(cL), mI = __ballot(cI);
            const int w = tid >> 6;
            const uint32_t lane = (uint32_t)tid & 63u;
            if (lane == 0) {
                wc[0][w] = (uint32_t)__popcll(mP);
                wc[1][w] = (uint32_t)__popcll(mH);
                wc[2][w] = (uint32_t)__popcll(mL);
                wc[3][w] = (uint32_t)__popcll(mI);
            }
            __syncthreads();
            if (tid < 4) {
                uint32_t e = 0;
                #pragma unroll
                for (int i = 0; i < 16; i++) { we_s[tid][i] = e; e += wc[tid][i]; }
                // totals of lanes 0..3 -> one packed 64-bit returning atomic
                uint32_t e0 = (uint32_t)__shfl((int)e, 0);
                uint32_t e1 = (uint32_t)__shfl((int)e, 1);
                uint32_t e2 = (uint32_t)__shfl((int)e, 2);
                uint32_t e3 = (uint32_t)__shfl((int)e, 3);
                if (tid == 0) {
                    ull add = (ull)e0 | ((ull)e1 << 16) | ((ull)e2 << 32) | ((ull)e3 << 48);
                    sPack = atomicAdd(&cnts[(size_t)ab * 8], add);
                }
            }
            __syncthreads();
            ull pk = sPack;
            uint32_t b0 = (uint32_t)(pk)       & 0xFFFFu;
            uint32_t b1 = (uint32_t)(pk >> 16) & 0xFFFFu;
            uint32_t b2 = (uint32_t)(pk >> 32) & 0xFFFFu;
            uint32_t b3 = (uint32_t)(pk >> 48) & 0xFFFFu;
            ull lt = lane ? (~0ull >> (64u - lane)) : 0ull;
            if (cP) slab[0 * NPROP + b0 + we_s[0][w] + (uint32_t)__popcll(mP & lt)] = entry;
            if (cH) slab[1 * NPROP + b1 + we_s[1][w] + (uint32_t)__popcll(mH & lt)] = entry;
            if (cL) slab[2 * NPROP + b2 + we_s[2][w] + (uint32_t)__popcll(mL & lt)] = entry;
            if (cI) slab[3 * NPROP + b3 + we_s[3][w] + (uint32_t)__popcll(mI & lt)] = entry;
            __syncthreads();   // protect wc/sPack reuse in next chunk
        }
    }

    // ================= software grid barrier (release/acquire) =================
    __syncthreads();
    if (tid == 0) {
        __threadfence();                                   // release our writes
        uint32_t arrived = atomicAdd(&bar[0], 1u) + 1u;
        if (arrived == (uint32_t)gridDim.x) {
            atomicExch(&bar[1], 1u);
        } else {
            while (atomicAdd(&bar[1], 0u) == 0u) __builtin_amdgcn_s_sleep(8);
        }
        __threadfence();                                   // acquire (inv caches)
    }
    __syncthreads();
    if (bid >= BATCH) return;

    // ================= select phase (r4-verified), block sb = batch =============
    const int sb = bid;
    const ull* Ppos  = lists + ((size_t)sb * 4 + 0) * NPROP;
    const ull* PnegH = lists + ((size_t)sb * 4 + 1) * NPROP;
    const ull* PnegL = lists + ((size_t)sb * 4 + 2) * NPROP;
    const ull* Pign  = lists + ((size_t)sb * 4 + 3) * NPROP;
    const ull pk = cnts[(size_t)sb * 8];
    const uint32_t npos = (uint32_t)(pk)       & 0xFFFFu;
    const uint32_t nH   = (uint32_t)(pk >> 16) & 0xFFFFu;
    const uint32_t nL   = (uint32_t)(pk >> 32) & 0xFFFFu;
    const uint32_t nig  = (uint32_t)(pk >> 48) & 0xFFFFu;
    const uint32_t nneg = nH + nL;
    const uint32_t npn  = npos + nneg;
    const bool inP = (npos <= PCAP);
    if (tid == 0) selc = 0;
    if (inP) for (uint32_t j = tid; j < npos; j += 1024) dpos[j] = Ppos[j];
    __syncthreads();

    auto posEnt = [&](uint32_t j) -> ull { return inP ? dpos[j] : Ppos[j]; };
    auto keyA_of = [](ull e) -> ull {    // raw (mant, invn): jnp stable argsort on r
        return (((e >> 21) & 0x7FFFFFull) << 14) | ((e >> 7) & 0x3FFFull);
    };

    auto locate = [&](uint32_t k) {      // boundary bin for k-th largest, wave 0
        if (tid < 64) {
            const uint32_t lane = (uint32_t)tid;
            uint32_t cs = 0;
            if (lane < 32) {
                const uint32_t base = lane * 64u;
                #pragma unroll 8
                for (uint32_t i = 0; i < 64; i++) cs += hist[base + i];
            }
            uint32_t s = cs;
            #pragma unroll
            for (int off = 1; off < 32; off <<= 1) {
                uint32_t t = __shfl_down(s, off);
                if (lane + off < 32) s += t;
            }
            uint32_t sExcl = s - cs;
            bool cond = (lane < 32) && (sExcl < k) && (k <= s);
            ull ball = __ballot(cond);
            uint32_t cstar = (uint32_t)(__ffsll((unsigned long long)ball) - 1);
            uint32_t kc = (uint32_t)__shfl((int)(k - sExcl), (int)cstar);
            uint32_t val = hist[cstar * 64u + lane];
            uint32_t fi = val;
            #pragma unroll
            for (int off = 1; off < 64; off <<= 1) {
                uint32_t t = __shfl_down(fi, off);
                if (lane + off < 64) fi += t;
            }
            uint32_t fExcl = fi - val;
            bool cond2 = (fExcl < kc) && (kc <= fi);
            ull ball2 = __ballot(cond2);
            uint32_t bstar = (uint32_t)(__ffsll((unsigned long long)ball2) - 1);
            if (lane == bstar) {
                sh_dig = cstar * 64u + lane;
                sh_k = kc - fExcl;
                sh_cnt_in = val;
            }
        }
    };

    // select k-th largest over m elements (key/elig via functor)
    auto radix = [&](auto&& kf, uint32_t m, uint32_t k, int shift) -> ull {
        if (m <= GCAP) {   // direct path: gather all eligible, rank-select
            if (tid == 0) gcnt = 0;
            __syncthreads();
            for (uint32_t j = tid; j < m; j += 1024) {
                bool e; ull key = kf(j, e);
                if (e) { uint32_t s = atomicAdd(&gcnt, 1u); gat[s] = key; }
            }
            __syncthreads();
            uint32_t gc = gcnt;
            if (tid < (int)gc) {
                ull x = gat[tid];
                uint32_t r = 0;
                for (uint32_t j = 0; j < gc; j++) r += (gat[j] > x);
                if (r == k - 1) sh_thr = x;
            }
            __syncthreads();
            return sh_thr;
        }
        ull prefix = 0, mask = 0;
        for (;;) {
            hist[tid] = 0; hist[tid + 1024] = 0;
            __syncthreads();
            for (uint32_t j = tid; j < m; j += 1024) {
                bool e; ull key = kf(j, e);
                if (e && ((key ^ prefix) & mask) == 0)
                    atomicAdd(&hist[(uint32_t)(key >> shift) & 2047u], 1u);
            }
            __syncthreads();
            locate(k);
            __syncthreads();
            uint32_t dig = sh_dig, kk = sh_k, cnt = sh_cnt_in;
            prefix |= ((ull)dig) << shift;
            mask   |= 2047ull << shift;
            if (cnt <= GCAP || shift == 0) {
                if (tid == 0) gcnt = 0;
                __syncthreads();
                for (uint32_t j = tid; j < m; j += 1024) {
                    bool e; ull key = kf(j, e);
                    if (e && ((key ^ prefix) & mask) == 0) {
                        uint32_t s = atomicAdd(&gcnt, 1u);
                        if (s < GCAP) gat[s] = key;
                    }
                }
                __syncthreads();
                uint32_t gc = (gcnt < GCAP) ? gcnt : GCAP;
                if (tid < (int)gc) {
                    ull x = gat[tid];
                    uint32_t r = 0;
                    for (uint32_t j = 0; j < gc; j++) r += (gat[j] > x);
                    if (r == kk - 1) sh_thr = x;
                }
                __syncthreads();
                return sh_thr;
            } else {
                k = kk;
                shift = (shift >= 11) ? shift - 11 : 0;
                __syncthreads();
            }
        }
    };

    // ---- phase 0: thrA = 64th-largest keyA among positives (only if npos > 64)
    ull thrA = 0;
    if (npos > NFG) {
        thrA = radix([&](uint32_t j, bool& e) -> ull {
            e = true; return keyA_of(posEnt(j)); }, npos, NFG, 26);
    }

    // exact jnp prio keys: f32 bits of (cls + r), rounding included
    auto keyB_pos = [&](ull ent) -> ull {
        uint32_t mant = (uint32_t)((ent >> 21) & 0x7FFFFFull);
        uint32_t invn = (uint32_t)((ent >> 7) & 0x3FFFull);
        float r = __uint_as_float(0x3F800000u | mant) - 1.0f;
        uint32_t cls = (keyA_of(ent) >= thrA) ? 3u : 1u;
        float prio = (float)cls + r;
        return (((ull)__float_as_uint(prio)) << 14) | (ull)invn;
    };
    auto keyB_neg = [](ull ent) -> ull {
        uint32_t mant = (uint32_t)((ent >> 21) & 0x7FFFFFull);
        uint32_t invn = (uint32_t)((ent >> 7) & 0x3FFFull);
        float r = __uint_as_float(0x3F800000u | mant) - 1.0f;
        float prio = 2.0f + r;
        return (((ull)__float_as_uint(prio)) << 14) | (ull)invn;
    };
    auto keyB_ign = [](ull ent) -> ull {
        uint32_t mant = (uint32_t)((ent >> 21) & 0x7FFFFFull);
        uint32_t invn = (uint32_t)((ent >> 7) & 0x3FFFull);
        float r = __uint_as_float(0x3F800000u | mant) - 1.0f;
        float prio = 0.0f + r;
        return (((ull)__float_as_uint(prio)) << 14) | (ull)invn;
    };

    // ---- phase 1: threshold for the 256-cut (boundary class analytic)
    const uint32_t c3 = (npos < NFG) ? npos : NFG;
    const uint32_t c2 = nneg;
    uint32_t clsStar = (npn >= NSAMP) ? ((NSAMP <= c3 + c2) ? 2u : 1u) : 0u;
    bool scanL = true;
    const bool scanI = (clsStar == 0u);
    ull thrB = 0;
    if (clsStar == 2u) {
        uint32_t k2 = NSAMP - c3;
        if (nH >= k2) {     // usual: top negatives all in the high slab
            scanL = false;  // negL keys provably < any negH key (strict sep at NEGT)
            thrB = radix([&](uint32_t j, bool& e) -> ull {
                e = true; return keyB_neg(PnegH[j]); }, nH, k2, 26);
        } else {            // fallback: virtual concat of both neg slabs
            thrB = radix([&](uint32_t j, bool& e) -> ull {
                e = true; return keyB_neg(j < nH ? PnegH[j] : PnegL[j - nH]); },
                nneg, k2, 26);
        }
    } else if (clsStar == 1u) {
        thrB = radix([&](uint32_t j, bool& e) -> ull {
            ull kb = keyB_pos(posEnt(j));
            e = ((kb >> 14) < 0x40000000ull);   // cls1 only (prio < 2.0)
            return kb; }, npos, NSAMP - c3 - c2, 26);
    } else {
        thrB = radix([&](uint32_t j, bool& e) -> ull {
            e = true; return keyB_ign(Pign[j]); }, nig, NSAMP - npn, 34);
    }
    __syncthreads();

    // ---- compact: exactly NSAMP keys (keys unique)
    auto push = [&](ull key, ull ent, uint32_t fg) {
        uint32_t s = atomicAdd(&selc, 1u);
        if (s < NSAMP) { selk[s] = key; sela[s] = (fg << 7) | (uint32_t)(ent & 0x7Full); }
    };
    for (uint32_t j = tid; j < npos; j += 1024) {
        ull ent = posEnt(j); ull key = keyB_pos(ent);
        if (clsStar == 0u || key >= thrB) push(key, ent, 1u);
    }
    for (uint32_t j = tid; j < nH; j += 1024) {
        ull ent = PnegH[j]; ull key = keyB_neg(ent);
        if (clsStar == 0u || key >= thrB) push(key, ent, 0u);
    }
    if (scanL) {
        for (uint32_t j = tid; j < nL; j += 1024) {
            ull ent = PnegL[j]; ull key = keyB_neg(ent);
            if (clsStar == 0u || key >= thrB) push(key, ent, 0u);
        }
    }
    if (scanI) {
        for (uint32_t j = tid; j < nig; j += 1024) {
            ull ent = Pign[j]; ull key = keyB_ign(ent);
            if (key >= thrB) push(key, ent, 0u);
        }
    }
    __syncthreads();

    // ---- rank-scatter: output row = count of greater keys (desc sort position)
    if (tid < NSAMP) {
        ull x = selk[tid];
        uint32_t r = 0;
        for (int j = 0; j < NSAMP; j++) r += (selk[j] > x);
        uint32_t n = 16383u - (uint32_t)(x & 0x3FFFull);
        uint32_t aux = sela[tid];
        uint32_t bg = aux & 0x7Fu;
        const int isfg = (int)((aux >> 7) & 1u);
        const float4 pb = ((const float4*)props)[(size_t)sb * NPROP + n];
        const float4 gb = ((const float4*)gts)[(size_t)sb * NGT + bg];
        const size_t O_ROI = 0;
        const size_t O_LBL = (size_t)BATCH * NSAMP * 4;
        const size_t O_TGT = O_LBL + (size_t)BATCH * NSAMP;
        const size_t O_INW = O_TGT + (size_t)BATCH * NSAMP * 4;
        const size_t O_OUW = O_INW + (size_t)BATCH * NSAMP * 4;
        const size_t row = (size_t)sb * NSAMP + r;
        out[O_ROI + row * 4 + 0] = pb.x;
        out[O_ROI + row * 4 + 1] = pb.y;
        out[O_ROI + row * 4 + 2] = pb.z;
        out[O_ROI + row * 4 + 3] = pb.w;
        out[O_LBL + row] = isfg ? 1.0f : 0.0f;
        float rw  = pb.z - pb.x, rh = pb.w - pb.y;
        float gw  = gb.z - gb.x, gh = gb.w - gb.y;
        out[O_TGT + row * 4 + 0] = ((gb.x + gb.z) * 0.5f - (pb.x + pb.z) * 0.5f) / rw;
        out[O_TGT + row * 4 + 1] = ((gb.y + gb.w) * 0.5f - (pb.y + pb.w) * 0.5f) / rh;
        out[O_TGT + row * 4 + 2] = logf(gw / rw);
        out[O_TGT + row * 4 + 3] = logf(gh / rh);
        float wv = isfg ? 1.0f : 0.0f;
        for (int c = 0; c < 4; c++) {
            out[O_INW + row * 4 + c] = wv;
            out[O_OUW + row * 4 + c] = wv;
        }
    }
}

extern "C" void kernel_launch(void* const* d_in, const int* in_sizes, int n_in,
                              void* d_out, int out_size, void* d_ws, size_t ws_size,
                              hipStream_t stream) {
    (void)in_sizes; (void)n_in; (void)out_size; (void)ws_size;
    const float* props = (const float*)d_in[0];
    const float* gts   = (const float*)d_in[1];
    ull* lists = (ull*)d_ws;                                    // 16*4*16384*8 = 8 MB
    ull* cnts  = (ull*)((char*)d_ws + (size_t)BATCH * 4 * NPROP * 8);  // stride-8 ull/batch
    uint32_t* bar = (uint32_t*)(cnts + BATCH * 8);              // 2 u32, own line
    float* out = (float*)d_out;

    k_init<<<1, 512, 0, stream>>>((uint32_t*)cnts);
    k_fused<<<256, 1024, 0, stream>>>(props, gts, lists, cnts, bar, out);
}

// Round 7
// 103.933 us; speedup vs baseline: 1.1499x; 1.1499x over previous
//
#include <hip/hip_runtime.h>
#include <stdint.h>

#define BATCH 16
#define NPROP 16384
#define NGT   128
#define NSAMP 256
#define NFG   64
#define GCAP  512
#define PCAP  8192   // dense pos LDS cap (64 KB)
#define HCAP  2048   // dense negH LDS cap (16 KB)
#define NBLK  128    // segments (k_compute blocks) per batch
#define BPB   128    // proposals per segment
#define NEGT  0x780002u  // neg high/low mant split; strict f32(2+r) separation (RNE)

typedef unsigned long long ull;

// ---------- threefry2x32 block (key 0,1) ----------
__device__ __forceinline__ void thr_block(uint32_t c0, uint32_t c1,
                                          uint32_t* o0, uint32_t* o1) {
    const uint32_t k0 = 0u, k1 = 1u, ks2 = 0x1BD11BDBu; // 0^1^0x1BD11BDA
    uint32_t x0 = c0 + k0, x1 = c1 + k1;
#define RND(d) { x0 += x1; x1 = (x1 << d) | (x1 >> (32 - d)); x1 ^= x0; }
    RND(13) RND(15) RND(26) RND(6)   x0 += k1;  x1 += ks2 + 1u;
    RND(17) RND(29) RND(16) RND(24)  x0 += ks2; x1 += k0 + 2u;
    RND(13) RND(15) RND(26) RND(6)   x0 += k0;  x1 += k1 + 3u;
    RND(17) RND(29) RND(16) RND(24)  x0 += k1;  x1 += ks2 + 4u;
    RND(13) RND(15) RND(26) RND(6)   x0 += ks2; x1 += k0 + 5u;
#undef RND
    *o0 = x0; *o1 = x1;
}

__device__ __forceinline__ uint32_t thr_part_xor(uint32_t f) {
    uint32_t a, b; thr_block(0u, f, &a, &b);
    return a ^ b;
}

// list entry (u64): [44]=isPos, [43:21]=r mantissa (bits>>9), [20:7]=16383-n, [6:0]=argmax gt
// slabs per batch: 0=pos, 1=negH (mant>=NEGT), 2=negL, 3=ign; entry at seg*BPB + local.
// cntblk[(b*NBLK+seg)*4 + cls] written NON-atomically every launch -> no zeroing kernel.
__global__ void __launch_bounds__(256) k_compute(
    const float* __restrict__ props, const float* __restrict__ gts,
    ull* __restrict__ lists, uint32_t* __restrict__ cntblk)
{
#pragma clang fp contract(off)
    const int b = blockIdx.y;
    const int blk = blockIdx.x;
    const int tid = threadIdx.x;
    const int half = tid & 1;                 // 2 lanes per proposal: GTs 0-63 / 64-127
    const int n = blk * BPB + (tid >> 1);
    // SoA GT tile, odd half at +65 so even/odd lanes hit disjoint banks (no conflicts)
    __shared__ float2 sA[130];   // (x1,y1)
    __shared__ float2 sB[130];   // (x2,y2)
    __shared__ float  sag[130];
    __shared__ uint32_t wc[4][4], we_s[4][4];
    if (tid < NGT) {
        float4 g = ((const float4*)gts)[(size_t)b * NGT + tid];
        int idx = (tid < 64) ? tid : tid + 1;
        sA[idx] = make_float2(g.x, g.y);
        sB[idx] = make_float2(g.z, g.w);
        sag[idx] = (g.z - g.x) * (g.w - g.y);
    }
    __syncthreads();
    const float4 pb = ((const float4*)props)[(size_t)b * NPROP + n];
    const float ap = (pb.z - pb.x) * (pb.w - pb.y);
    float best = -1.0f; int bg = 0;
    const int base  = half ? 65 : 0;
    const int gbias = half ? 64 : 0;
    #pragma unroll 4
    for (int i = 0; i < 64; ++i) {
        const float2 a = sA[base + i];
        const float2 c = sB[base + i];
        float w  = fmaxf(fminf(pb.z, c.x) - fmaxf(pb.x, a.x), 0.0f);
        float hh = fmaxf(fminf(pb.w, c.y) - fmaxf(pb.y, a.y), 0.0f);
        float inter = w * hh;
        float un = fmaxf(ap + sag[base + i] - inter, 1e-8f);
        float iou = inter / un;                   // IEEE f32 div = numpy bits
        if (iou > best) { best = iou; bg = gbias + i; }  // first-max within half
    }
    // merge halves: even lane owns result; strict > keeps half0 on float-ties (lower gt idx)
    float ob = __shfl_xor(best, 1);
    int  obg = __shfl_xor(bg, 1);
    if (half == 0 && ob > best) { best = ob; bg = obg; }

    uint32_t lab = (best >= 0.5f) ? 2u : ((best < 0.1f) ? 1u : 0u);
    const uint32_t f = (uint32_t)b * NPROP + (uint32_t)n;
    uint32_t mant = thr_part_xor(f) >> 9;
    ull entry = ((ull)(lab == 2u) << 44) | ((ull)mant << 21)
              | ((ull)(16383u - (uint32_t)n) << 7) | (ull)(uint32_t)bg;

    const bool isEven = (half == 0);
    bool cP = isEven && (lab == 2u);
    bool cH = isEven && (lab == 1u) && (mant >= NEGT);
    bool cL = isEven && (lab == 1u) && (mant <  NEGT);
    bool cI = isEven && (lab == 0u);
    ull mP = __ballot(cP), mH = __ballot(cH), mL = __ballot(cL), mI = __ballot(cI);
    const int w = tid >> 6;
    const uint32_t lane = (uint32_t)tid & 63u;
    if (lane == 0) {
        wc[0][w] = (uint32_t)__popcll(mP);
        wc[1][w] = (uint32_t)__popcll(mH);
        wc[2][w] = (uint32_t)__popcll(mL);
        wc[3][w] = (uint32_t)__popcll(mI);
    }
    __syncthreads();
    if (tid < 4) {       // per-seg NON-atomic counts: every slot written -> no k_zero
        uint32_t e = 0;
        #pragma unroll
        for (int i = 0; i < 4; i++) { we_s[tid][i] = e; e += wc[tid][i]; }
        cntblk[((size_t)b * NBLK + blk) * 4 + tid] = e;
    }
    __syncthreads();
    ull lt = lane ? (~0ull >> (64u - lane)) : 0ull;
    ull* slab = lists + (size_t)b * 4 * NPROP;
    const uint32_t segB = (uint32_t)blk * BPB;
    if (cP) slab[0 * NPROP + segB + we_s[0][w] + (uint32_t)__popcll(mP & lt)] = entry;
    if (cH) slab[1 * NPROP + segB + we_s[1][w] + (uint32_t)__popcll(mH & lt)] = entry;
    if (cL) slab[2 * NPROP + segB + we_s[2][w] + (uint32_t)__popcll(mL & lt)] = entry;
    if (cI) slab[3 * NPROP + segB + we_s[3][w] + (uint32_t)__popcll(mI & lt)] = entry;
}

__global__ void __launch_bounds__(1024) k_select(
    const float* __restrict__ props, const float* __restrict__ gts,
    const ull* __restrict__ lists, const uint32_t* __restrict__ cntblk,
    float* __restrict__ out)
{
#pragma clang fp contract(off)
    const int b = blockIdx.x;
    const int tid = threadIdx.x;
    const int wid = tid >> 6;
    const uint32_t lane = (uint32_t)tid & 63u;
    __shared__ ull      dpos[PCAP];      // 64 KB dense pos
    __shared__ ull      dnh[HCAP];       // 16 KB dense negH
    __shared__ uint32_t hist[2048];      // 8 KB
    __shared__ ull      gat[GCAP];       // 4 KB
    __shared__ ull      selk[NSAMP];     // 2 KB
    __shared__ uint32_t sela[NSAMP];     // 1 KB
    __shared__ uint32_t bc[NBLK * 4];    // 2 KB per-seg counts
    __shared__ uint32_t tot[4];
    __shared__ uint32_t sh_dig, sh_k, sh_cnt_in, gcnt, selc, stP, stH;
    __shared__ ull sh_thr;

    const ull* Spos = lists + ((size_t)b * 4 + 0) * NPROP;
    const ull* SnH  = lists + ((size_t)b * 4 + 1) * NPROP;
    const ull* SnL  = lists + ((size_t)b * 4 + 2) * NPROP;
    const ull* Sign = lists + ((size_t)b * 4 + 3) * NPROP;
    if (tid < 4) tot[tid] = 0;
    if (tid == 0) { selc = 0; stP = 0; stH = 0; }
    __syncthreads();
    if (tid < NBLK * 4) {
        uint32_t v = cntblk[(size_t)b * NBLK * 4 + tid];
        bc[tid] = v;
        atomicAdd(&tot[tid & 3], v);
    }
    __syncthreads();
    const uint32_t npos = tot[0], nH = tot[1], nL = tot[2], nig = tot[3];
    const uint32_t nneg = nH + nL;
    const uint32_t npn  = npos + nneg;
    const bool dP = (npos <= PCAP), dH = (nH <= HCAP);

    // stage pos/negH dense into LDS: each wave walks 8 segments, wave-agg slot alloc
    {
        for (int s8 = 0; s8 < 8; ++s8) {
            uint32_t seg = (uint32_t)(wid * 8 + s8);
            if (dP) {
                uint32_t c = bc[seg * 4 + 0];
                for (uint32_t i0 = 0; i0 < c; i0 += 64) {
                    uint32_t take = (c - i0 < 64u) ? (c - i0) : 64u;
                    uint32_t s0 = 0;
                    if (lane == 0) s0 = atomicAdd(&stP, take);
                    s0 = (uint32_t)__shfl((int)s0, 0);
                    if (lane < take) dpos[s0 + lane] = Spos[seg * BPB + i0 + lane];
                }
            }
            if (dH) {
                uint32_t c = bc[seg * 4 + 1];
                for (uint32_t i0 = 0; i0 < c; i0 += 64) {
                    uint32_t take = (c - i0 < 64u) ? (c - i0) : 64u;
                    uint32_t s0 = 0;
                    if (lane == 0) s0 = atomicAdd(&stH, take);
                    s0 = (uint32_t)__shfl((int)s0, 0);
                    if (lane < take) dnh[s0 + lane] = SnH[seg * BPB + i0 + lane];
                }
            }
        }
    }
    __syncthreads();

    // accessors: dense LDS (usual) or masked segmented global (fallback)
    const uint32_t MSEG = NBLK * BPB;
    const uint32_t mPos = dP ? npos : MSEG;
    const uint32_t mH   = dH ? nH   : MSEG;
    auto posEnt = [&](uint32_t j, bool& e) -> ull {
        if (dP) { e = true; return dpos[j]; }
        e = (j & (BPB - 1u)) < bc[(j >> 7) * 4 + 0];
        return e ? Spos[j] : 0ull;
    };
    auto nhEnt = [&](uint32_t j, bool& e) -> ull {
        if (dH) { e = true; return dnh[j]; }
        e = (j & (BPB - 1u)) < bc[(j >> 7) * 4 + 1];
        return e ? SnH[j] : 0ull;
    };
    auto nlEnt = [&](uint32_t j, bool& e) -> ull {
        e = (j & (BPB - 1u)) < bc[(j >> 7) * 4 + 2];
        return e ? SnL[j] : 0ull;
    };
    auto igEnt = [&](uint32_t j, bool& e) -> ull {
        e = (j & (BPB - 1u)) < bc[(j >> 7) * 4 + 3];
        return e ? Sign[j] : 0ull;
    };

    auto keyA_of = [](ull e) -> ull {    // raw (mant, invn): jnp stable argsort on r
        return (((e >> 21) & 0x7FFFFFull) << 14) | ((e >> 7) & 0x3FFFull);
    };

    auto locate = [&](uint32_t k) {      // boundary bin for k-th largest, wave 0
        if (tid < 64) {
            uint32_t cs = 0;
            if (lane < 32) {
                const uint32_t base = lane * 64u;
                #pragma unroll 8
                for (uint32_t i = 0; i < 64; i++)
                    cs += hist[base + ((i + lane) & 63u)];   // rotated: conflict-free
            }
            uint32_t s = cs;
            #pragma unroll
            for (int off = 1; off < 32; off <<= 1) {
                uint32_t t = __shfl_down(s, off);
                if (lane + off < 32) s += t;
            }
            uint32_t sExcl = s - cs;
            bool cond = (lane < 32) && (sExcl < k) && (k <= s);
            ull ball = __ballot(cond);
            uint32_t cstar = (uint32_t)(__ffsll((unsigned long long)ball) - 1);
            uint32_t kc = (uint32_t)__shfl((int)(k - sExcl), (int)cstar);
            uint32_t val = hist[cstar * 64u + lane];
            uint32_t fi = val;
            #pragma unroll
            for (int off = 1; off < 64; off <<= 1) {
                uint32_t t = __shfl_down(fi, off);
                if (lane + off < 64) fi += t;
            }
            uint32_t fExcl = fi - val;
            bool cond2 = (fExcl < kc) && (kc <= fi);
            ull ball2 = __ballot(cond2);
            uint32_t bstar = (uint32_t)(__ffsll((unsigned long long)ball2) - 1);
            if (lane == bstar) {
                sh_dig = cstar * 64u + lane;
                sh_k = kc - fExcl;
                sh_cnt_in = val;
            }
        }
    };

    // select k-th largest over m elements (key/elig via functor)
    auto radix = [&](auto&& kf, uint32_t m, uint32_t k, int shift) -> ull {
        if (m <= GCAP) {   // direct path: gather all eligible, rank-select
            if (tid == 0) gcnt = 0;
            __syncthreads();
            for (uint32_t j = tid; j < m; j += 1024) {
                bool e; ull key = kf(j, e);
                if (e) { uint32_t s = atomicAdd(&gcnt, 1u); gat[s] = key; }
            }
            __syncthreads();
            uint32_t gc = gcnt;
            if (tid < (int)gc) {
                ull x = gat[tid];
                uint32_t r = 0;
                for (uint32_t j = 0; j < gc; j++) r += (gat[j] > x);
                if (r == k - 1) sh_thr = x;
            }
            __syncthreads();
            return sh_thr;
        }
        ull prefix = 0, mask = 0;
        for (;;) {
            hist[tid] = 0; hist[tid + 1024] = 0;
            __syncthreads();
            for (uint32_t j = tid; j < m; j += 1024) {
                bool e; ull key = kf(j, e);
                if (e && ((key ^ prefix) & mask) == 0)
                    atomicAdd(&hist[(uint32_t)(key >> shift) & 2047u], 1u);
            }
            __syncthreads();
            locate(k);
            __syncthreads();
            uint32_t dig = sh_dig, kk = sh_k, cnt = sh_cnt_in;
            prefix |= ((ull)dig) << shift;
            mask   |= 2047ull << shift;
            if (cnt <= GCAP || shift == 0) {
                if (tid == 0) gcnt = 0;
                __syncthreads();
                for (uint32_t j = tid; j < m; j += 1024) {
                    bool e; ull key = kf(j, e);
                    if (e && ((key ^ prefix) & mask) == 0) {
                        uint32_t s = atomicAdd(&gcnt, 1u);
                        if (s < GCAP) gat[s] = key;
                    }
                }
                __syncthreads();
                uint32_t gc = (gcnt < GCAP) ? gcnt : GCAP;
                if (tid < (int)gc) {
                    ull x = gat[tid];
                    uint32_t r = 0;
                    for (uint32_t j = 0; j < gc; j++) r += (gat[j] > x);
                    if (r == kk - 1) sh_thr = x;
                }
                __syncthreads();
                return sh_thr;
            } else {
                k = kk;
                shift = (shift >= 11) ? shift - 11 : 0;
                __syncthreads();
            }
        }
    };

    // ---- phase 0: thrA = 64th-largest keyA among positives (only if npos > 64)
    ull thrA = 0;
    if (npos > NFG) {
        thrA = radix([&](uint32_t j, bool& e) -> ull {
            ull ent = posEnt(j, e); return keyA_of(ent); }, mPos, NFG, 26);
    }

    // exact jnp prio keys: f32 bits of (cls + r), rounding included
    auto keyB_pos = [&](ull ent) -> ull {
        uint32_t mant = (uint32_t)((ent >> 21) & 0x7FFFFFull);
        uint32_t invn = (uint32_t)((ent >> 7) & 0x3FFFull);
        float r = __uint_as_float(0x3F800000u | mant) - 1.0f;
        uint32_t cls = (keyA_of(ent) >= thrA) ? 3u : 1u;
        float prio = (float)cls + r;
        return (((ull)__float_as_uint(prio)) << 14) | (ull)invn;
    };
    auto keyB_neg = [](ull ent) -> ull {
        uint32_t mant = (uint32_t)((ent >> 21) & 0x7FFFFFull);
        uint32_t invn = (uint32_t)((ent >> 7) & 0x3FFFull);
        float r = __uint_as_float(0x3F800000u | mant) - 1.0f;
        float prio = 2.0f + r;
        return (((ull)__float_as_uint(prio)) << 14) | (ull)invn;
    };
    auto keyB_ign = [](ull ent) -> ull {
        uint32_t mant = (uint32_t)((ent >> 21) & 0x7FFFFFull);
        uint32_t invn = (uint32_t)((ent >> 7) & 0x3FFFull);
        float r = __uint_as_float(0x3F800000u | mant) - 1.0f;
        float prio = 0.0f + r;
        return (((ull)__float_as_uint(prio)) << 14) | (ull)invn;
    };

    // ---- phase 1: threshold for the 256-cut (boundary class analytic)
    const uint32_t c3 = (npos < NFG) ? npos : NFG;
    const uint32_t c2 = nneg;
    uint32_t clsStar = (npn >= NSAMP) ? ((NSAMP <= c3 + c2) ? 2u : 1u) : 0u;
    bool scanL = true;
    const bool scanI = (clsStar == 0u);
    ull thrB = 0;
    if (clsStar == 2u) {
        uint32_t k2 = NSAMP - c3;
        if (nH >= k2) {     // usual: top negatives all in the high slab
            scanL = false;  // negL keys provably < any negH key (strict sep at NEGT)
            // shift 26: bin = bits[22:12] + carry -> monotone (incl. 3.0 carry)
            thrB = radix([&](uint32_t j, bool& e) -> ull {
                ull ent = nhEnt(j, e); return keyB_neg(ent); }, mH, k2, 26);
        } else {            // fallback: virtual concat negH ++ negL (masked segmented)
            thrB = radix([&](uint32_t j, bool& e) -> ull {
                if (j < mH) { ull ent = nhEnt(j, e); return keyB_neg(ent); }
                ull ent = nlEnt(j - mH, e); return keyB_neg(ent); },
                mH + MSEG, k2, 26);
        }
    } else if (clsStar == 1u) {
        thrB = radix([&](uint32_t j, bool& e) -> ull {
            ull ent = posEnt(j, e);
            ull kb = keyB_pos(ent);
            e = e && ((kb >> 14) < 0x40000000ull);   // cls1 only (prio < 2.0)
            return kb; }, mPos, NSAMP - c3 - c2, 26);
    } else {
        thrB = radix([&](uint32_t j, bool& e) -> ull {
            ull ent = igEnt(j, e); return keyB_ign(ent); }, MSEG, NSAMP - npn, 34);
    }
    __syncthreads();

    // ---- compact: exactly NSAMP keys (keys unique)
    auto push = [&](ull key, ull ent, uint32_t fg) {
        uint32_t s = atomicAdd(&selc, 1u);
        if (s < NSAMP) { selk[s] = key; sela[s] = (fg << 7) | (uint32_t)(ent & 0x7Full); }
    };
    for (uint32_t j = tid; j < mPos; j += 1024) {
        bool e; ull ent = posEnt(j, e);
        if (!e) continue;
        ull key = keyB_pos(ent);
        if (clsStar == 0u || key >= thrB) push(key, ent, 1u);
    }
    for (uint32_t j = tid; j < mH; j += 1024) {
        bool e; ull ent = nhEnt(j, e);
        if (!e) continue;
        ull key = keyB_neg(ent);
        if (clsStar == 0u || key >= thrB) push(key, ent, 0u);
    }
    if (scanL) {
        for (uint32_t j = tid; j < MSEG; j += 1024) {
            bool e; ull ent = nlEnt(j, e);
            if (!e) continue;
            ull key = keyB_neg(ent);
            if (clsStar == 0u || key >= thrB) push(key, ent, 0u);
        }
    }
    if (scanI) {
        for (uint32_t j = tid; j < MSEG; j += 1024) {
            bool e; ull ent = igEnt(j, e);
            if (!e) continue;
            ull key = keyB_ign(ent);
            if (key >= thrB) push(key, ent, 0u);
        }
    }
    __syncthreads();

    // ---- rank-scatter: output row = count of greater keys (desc sort position)
    if (tid < NSAMP) {
        ull x = selk[tid];
        uint32_t r = 0;
        for (int j = 0; j < NSAMP; j++) r += (selk[j] > x);
        uint32_t n = 16383u - (uint32_t)(x & 0x3FFFull);
        uint32_t aux = sela[tid];
        uint32_t bg = aux & 0x7Fu;
        const int isfg = (int)((aux >> 7) & 1u);
        const float4 pb = ((const float4*)props)[(size_t)b * NPROP + n];
        const float4 gb = ((const float4*)gts)[(size_t)b * NGT + bg];
        const size_t O_ROI = 0;
        const size_t O_LBL = (size_t)BATCH * NSAMP * 4;
        const size_t O_TGT = O_LBL + (size_t)BATCH * NSAMP;
        const size_t O_INW = O_TGT + (size_t)BATCH * NSAMP * 4;
        const size_t O_OUW = O_INW + (size_t)BATCH * NSAMP * 4;
        const size_t row = (size_t)b * NSAMP + r;
        out[O_ROI + row * 4 + 0] = pb.x;
        out[O_ROI + row * 4 + 1] = pb.y;
        out[O_ROI + row * 4 + 2] = pb.z;
        out[O_ROI + row * 4 + 3] = pb.w;
        out[O_LBL + row] = isfg ? 1.0f : 0.0f;
        float rw  = pb.z - pb.x, rh = pb.w - pb.y;
        float gw  = gb.z - gb.x, gh = gb.w - gb.y;
        out[O_TGT + row * 4 + 0] = ((gb.x + gb.z) * 0.5f - (pb.x + pb.z) * 0.5f) / rw;
        out[O_TGT + row * 4 + 1] = ((gb.y + gb.w) * 0.5f - (pb.y + pb.w) * 0.5f) / rh;
        out[O_TGT + row * 4 + 2] = logf(gw / rw);
        out[O_TGT + row * 4 + 3] = logf(gh / rh);
        float wv = isfg ? 1.0f : 0.0f;
        for (int c = 0; c < 4; c++) {
            out[O_INW + row * 4 + c] = wv;
            out[O_OUW + row * 4 + c] = wv;
        }
    }
}

extern "C" void kernel_launch(void* const* d_in, const int* in_sizes, int n_in,
                              void* d_out, int out_size, void* d_ws, size_t ws_size,
                              hipStream_t stream) {
    (void)in_sizes; (void)n_in; (void)out_size; (void)ws_size;
    const float* props = (const float*)d_in[0];
    const float* gts   = (const float*)d_in[1];
    ull* lists = (ull*)d_ws;                                       // 16*4*16384*8 = 8 MB
    uint32_t* cntblk = (uint32_t*)((char*)d_ws + (size_t)BATCH * 4 * NPROP * 8); // 32 KB
    float* out = (float*)d_out;

    dim3 gridA(NBLK, BATCH);   // (128, 16), 256 threads: 2 lanes/proposal
    k_compute<<<gridA, 256, 0, stream>>>(props, gts, lists, cntblk);
    k_select<<<BATCH, 1024, 0, stream>>>(props, gts, lists, cntblk, out);
}

// Round 8
// 102.461 us; speedup vs baseline: 1.1665x; 1.0144x over previous
//
#include <hip/hip_runtime.h>
#include <stdint.h>

#define BATCH 16
#define NPROP 16384
#define NGT   128
#define NSAMP 256
#define NFG   64
#define GCAP  512
#define PCAP  8192   // dense pos LDS cap (64 KB)
#define HCAP  2048   // dense negH LDS cap (16 KB)
#define NBLK  64     // segments (k_compute blocks) per batch
#define BPB   256    // proposals per segment
#define LOGB  8      // log2(BPB)
#define NEGT  0x780002u  // neg high/low mant split; strict f32(2+r) separation (RNE)

typedef unsigned long long ull;

// ---------- threefry2x32 block (key 0,1) ----------
__device__ __forceinline__ void thr_block(uint32_t c0, uint32_t c1,
                                          uint32_t* o0, uint32_t* o1) {
    const uint32_t k0 = 0u, k1 = 1u, ks2 = 0x1BD11BDBu; // 0^1^0x1BD11BDA
    uint32_t x0 = c0 + k0, x1 = c1 + k1;
#define RND(d) { x0 += x1; x1 = (x1 << d) | (x1 >> (32 - d)); x1 ^= x0; }
    RND(13) RND(15) RND(26) RND(6)   x0 += k1;  x1 += ks2 + 1u;
    RND(17) RND(29) RND(16) RND(24)  x0 += ks2; x1 += k0 + 2u;
    RND(13) RND(15) RND(26) RND(6)   x0 += k0;  x1 += k1 + 3u;
    RND(17) RND(29) RND(16) RND(24)  x0 += k1;  x1 += ks2 + 4u;
    RND(13) RND(15) RND(26) RND(6)   x0 += ks2; x1 += k0 + 5u;
#undef RND
    *o0 = x0; *o1 = x1;
}

__device__ __forceinline__ uint32_t thr_part_xor(uint32_t f) {
    uint32_t a, b; thr_block(0u, f, &a, &b);
    return a ^ b;
}

// list entry (u64): [44]=isPos, [43:21]=r mantissa (bits>>9), [20:7]=16383-n, [6:0]=argmax gt
// slabs per batch: 0=pos, 1=negH (mant>=NEGT), 2=negL, 3=ign; entry at seg*BPB + local.
// cntblk[(b*NBLK+seg)*4 + cls] written NON-atomically every launch -> no zeroing kernel.
__global__ void __launch_bounds__(256) k_compute(
    const float* __restrict__ props, const float* __restrict__ gts,
    ull* __restrict__ lists, uint32_t* __restrict__ cntblk)
{
#pragma clang fp contract(off)
    const int b = blockIdx.y;
    const int blk = blockIdx.x;
    const int tid = threadIdx.x;
    const int n = blk * BPB + tid;         // 1 proposal per lane (r0-proven form)
    __shared__ float4 g4[NGT];
    __shared__ uint32_t wc[4][4], we_s[4][4];
    if (tid < NGT)
        g4[tid] = ((const float4*)gts)[(size_t)b * NGT + tid];
    __syncthreads();
    const float4 pb = ((const float4*)props)[(size_t)b * NPROP + n];
    const float ap = (pb.z - pb.x) * (pb.w - pb.y);
    float best = -1.0f; int bg = 0;
    #pragma unroll 4
    for (int i = 0; i < NGT; ++i) {
        const float4 gb = g4[i];            // wave-uniform broadcast read
        float ag = (gb.z - gb.x) * (gb.w - gb.y);
        float w  = fmaxf(fminf(pb.z, gb.z) - fmaxf(pb.x, gb.x), 0.0f);
        float hh = fmaxf(fminf(pb.w, gb.w) - fmaxf(pb.y, gb.y), 0.0f);
        float inter = w * hh;
        float un = fmaxf(ap + ag - inter, 1e-8f);
        float iou = inter / un;             // IEEE f32 div = numpy bits
        if (iou > best) { best = iou; bg = i; }   // first-max = argmax
    }
    uint32_t lab = (best >= 0.5f) ? 2u : ((best < 0.1f) ? 1u : 0u);
    const uint32_t f = (uint32_t)b * NPROP + (uint32_t)n;
    uint32_t mant = thr_part_xor(f) >> 9;
    ull entry = ((ull)(lab == 2u) << 44) | ((ull)mant << 21)
              | ((ull)(16383u - (uint32_t)n) << 7) | (ull)(uint32_t)bg;

    bool cP = (lab == 2u);
    bool cH = (lab == 1u) && (mant >= NEGT);
    bool cL = (lab == 1u) && (mant <  NEGT);
    bool cI = (lab == 0u);
    ull mP = __ballot(cP), mH = __ballot(cH), mL = __ballot(cL), mI = __ballot(cI);
    const int w = tid >> 6;
    const uint32_t lane = (uint32_t)tid & 63u;
    if (lane == 0) {
        wc[0][w] = (uint32_t)__popcll(mP);
        wc[1][w] = (uint32_t)__popcll(mH);
        wc[2][w] = (uint32_t)__popcll(mL);
        wc[3][w] = (uint32_t)__popcll(mI);
    }
    __syncthreads();
    if (tid < 4) {       // per-seg NON-atomic counts: every slot written every launch
        uint32_t e = 0;
        #pragma unroll
        for (int i = 0; i < 4; i++) { we_s[tid][i] = e; e += wc[tid][i]; }
        cntblk[((size_t)b * NBLK + blk) * 4 + tid] = e;
    }
    __syncthreads();
    ull lt = lane ? (~0ull >> (64u - lane)) : 0ull;
    ull* slab = lists + (size_t)b * 4 * NPROP;
    const uint32_t segB = (uint32_t)blk * BPB;
    if (cP) slab[0 * NPROP + segB + we_s[0][w] + (uint32_t)__popcll(mP & lt)] = entry;
    if (cH) slab[1 * NPROP + segB + we_s[1][w] + (uint32_t)__popcll(mH & lt)] = entry;
    if (cL) slab[2 * NPROP + segB + we_s[2][w] + (uint32_t)__popcll(mL & lt)] = entry;
    if (cI) slab[3 * NPROP + segB + we_s[3][w] + (uint32_t)__popcll(mI & lt)] = entry;
}

__global__ void __launch_bounds__(1024) k_select(
    const float* __restrict__ props, const float* __restrict__ gts,
    const ull* __restrict__ lists, const uint32_t* __restrict__ cntblk,
    float* __restrict__ out)
{
#pragma clang fp contract(off)
    const int b = blockIdx.x;
    const int tid = threadIdx.x;
    const int wid = tid >> 6;
    const uint32_t lane = (uint32_t)tid & 63u;
    __shared__ ull      dpos[PCAP];      // 64 KB dense pos
    __shared__ ull      dnh[HCAP];       // 16 KB dense negH
    __shared__ uint32_t hist[2048];      // 8 KB
    __shared__ ull      gat[GCAP];       // 4 KB
    __shared__ ull      selk[NSAMP];     // 2 KB
    __shared__ uint32_t sela[NSAMP];     // 1 KB
    __shared__ uint32_t bc[NBLK * 4];    // 1 KB per-seg counts
    __shared__ uint32_t tot[4];
    __shared__ uint32_t sh_dig, sh_k, sh_cnt_in, gcnt, selc, stP, stH;
    __shared__ ull sh_thr;

    const ull* Spos = lists + ((size_t)b * 4 + 0) * NPROP;
    const ull* SnH  = lists + ((size_t)b * 4 + 1) * NPROP;
    const ull* SnL  = lists + ((size_t)b * 4 + 2) * NPROP;
    const ull* Sign = lists + ((size_t)b * 4 + 3) * NPROP;
    if (tid == 0) { selc = 0; stP = 0; stH = 0; }
    if (tid < NBLK * 4) bc[tid] = cntblk[(size_t)b * NBLK * 4 + tid];
    __syncthreads();
    if (tid < 4) {                       // serial per-class totals (64 iters, trivial)
        uint32_t run = 0;
        for (int blk = 0; blk < NBLK; ++blk) run += bc[blk * 4 + tid];
        tot[tid] = run;
    }
    __syncthreads();
    const uint32_t npos = tot[0], nH = tot[1], nL = tot[2], nig = tot[3];
    const uint32_t nneg = nH + nL;
    const uint32_t npn  = npos + nneg;
    const bool dP = (npos <= PCAP), dH = (nH <= HCAP);

    // stage pos/negH dense into LDS: each wave walks 4 segments, wave-agg slot alloc
    for (int s4 = 0; s4 < 4; ++s4) {
        uint32_t seg = (uint32_t)(wid * 4 + s4);
        if (dP) {
            uint32_t c = bc[seg * 4 + 0];
            for (uint32_t i0 = 0; i0 < c; i0 += 64) {
                uint32_t take = (c - i0 < 64u) ? (c - i0) : 64u;
                uint32_t s0 = 0;
                if (lane == 0) s0 = atomicAdd(&stP, take);
                s0 = (uint32_t)__shfl((int)s0, 0);
                if (lane < take) dpos[s0 + lane] = Spos[seg * BPB + i0 + lane];
            }
        }
        if (dH) {
            uint32_t c = bc[seg * 4 + 1];
            for (uint32_t i0 = 0; i0 < c; i0 += 64) {
                uint32_t take = (c - i0 < 64u) ? (c - i0) : 64u;
                uint32_t s0 = 0;
                if (lane == 0) s0 = atomicAdd(&stH, take);
                s0 = (uint32_t)__shfl((int)s0, 0);
                if (lane < take) dnh[s0 + lane] = SnH[seg * BPB + i0 + lane];
            }
        }
    }
    __syncthreads();

    // accessors: dense LDS (usual) or masked segmented global (fallback)
    const uint32_t MSEG = NBLK * BPB;
    const uint32_t mPos = dP ? npos : MSEG;
    const uint32_t mH   = dH ? nH   : MSEG;
    auto posEnt = [&](uint32_t j, bool& e) -> ull {
        if (dP) { e = true; return dpos[j]; }
        e = (j & (BPB - 1u)) < bc[(j >> LOGB) * 4 + 0];
        return e ? Spos[j] : 0ull;
    };
    auto nhEnt = [&](uint32_t j, bool& e) -> ull {
        if (dH) { e = true; return dnh[j]; }
        e = (j & (BPB - 1u)) < bc[(j >> LOGB) * 4 + 1];
        return e ? SnH[j] : 0ull;
    };
    auto nlEnt = [&](uint32_t j, bool& e) -> ull {
        e = (j & (BPB - 1u)) < bc[(j >> LOGB) * 4 + 2];
        return e ? SnL[j] : 0ull;
    };
    auto igEnt = [&](uint32_t j, bool& e) -> ull {
        e = (j & (BPB - 1u)) < bc[(j >> LOGB) * 4 + 3];
        return e ? Sign[j] : 0ull;
    };

    auto keyA_of = [](ull e) -> ull {    // raw (mant, invn): jnp stable argsort on r
        return (((e >> 21) & 0x7FFFFFull) << 14) | ((e >> 7) & 0x3FFFull);
    };

    auto locate = [&](uint32_t k) {      // boundary bin for k-th largest, wave 0
        if (tid < 64) {
            uint32_t cs = 0;
            if (lane < 32) {
                const uint32_t base = lane * 64u;
                #pragma unroll 8
                for (uint32_t i = 0; i < 64; i++)
                    cs += hist[base + ((i + lane) & 63u)];   // rotated: conflict-free
            }
            uint32_t s = cs;
            #pragma unroll
            for (int off = 1; off < 32; off <<= 1) {
                uint32_t t = __shfl_down(s, off);
                if (lane + off < 32) s += t;
            }
            uint32_t sExcl = s - cs;
            bool cond = (lane < 32) && (sExcl < k) && (k <= s);
            ull ball = __ballot(cond);
            uint32_t cstar = (uint32_t)(__ffsll((unsigned long long)ball) - 1);
            uint32_t kc = (uint32_t)__shfl((int)(k - sExcl), (int)cstar);
            uint32_t val = hist[cstar * 64u + lane];
            uint32_t fi = val;
            #pragma unroll
            for (int off = 1; off < 64; off <<= 1) {
                uint32_t t = __shfl_down(fi, off);
                if (lane + off < 64) fi += t;
            }
            uint32_t fExcl = fi - val;
            bool cond2 = (fExcl < kc) && (kc <= fi);
            ull ball2 = __ballot(cond2);
            uint32_t bstar = (uint32_t)(__ffsll((unsigned long long)ball2) - 1);
            if (lane == bstar) {
                sh_dig = cstar * 64u + lane;
                sh_k = kc - fExcl;
                sh_cnt_in = val;
            }
        }
    };

    // select k-th largest over m elements (key/elig via functor)
    auto radix = [&](auto&& kf, uint32_t m, uint32_t k, int shift) -> ull {
        if (m <= GCAP) {   // direct path: gather all eligible, rank-select
            if (tid == 0) gcnt = 0;
            __syncthreads();
            for (uint32_t j = tid; j < m; j += 1024) {
                bool e; ull key = kf(j, e);
                if (e) { uint32_t s = atomicAdd(&gcnt, 1u); gat[s] = key; }
            }
            __syncthreads();
            uint32_t gc = gcnt;
            if (tid < (int)gc) {
                ull x = gat[tid];
                uint32_t r = 0;
                for (uint32_t j = 0; j < gc; j++) r += (gat[j] > x);
                if (r == k - 1) sh_thr = x;
            }
            __syncthreads();
            return sh_thr;
        }
        ull prefix = 0, mask = 0;
        for (;;) {
            hist[tid] = 0; hist[tid + 1024] = 0;
            __syncthreads();
            for (uint32_t j = tid; j < m; j += 1024) {
                bool e; ull key = kf(j, e);
                if (e && ((key ^ prefix) & mask) == 0)
                    atomicAdd(&hist[(uint32_t)(key >> shift) & 2047u], 1u);
            }
            __syncthreads();
            locate(k);
            __syncthreads();
            uint32_t dig = sh_dig, kk = sh_k, cnt = sh_cnt_in;
            prefix |= ((ull)dig) << shift;
            mask   |= 2047ull << shift;
            if (cnt <= GCAP || shift == 0) {
                if (tid == 0) gcnt = 0;
                __syncthreads();
                for (uint32_t j = tid; j < m; j += 1024) {
                    bool e; ull key = kf(j, e);
                    if (e && ((key ^ prefix) & mask) == 0) {
                        uint32_t s = atomicAdd(&gcnt, 1u);
                        if (s < GCAP) gat[s] = key;
                    }
                }
                __syncthreads();
                uint32_t gc = (gcnt < GCAP) ? gcnt : GCAP;
                if (tid < (int)gc) {
                    ull x = gat[tid];
                    uint32_t r = 0;
                    for (uint32_t j = 0; j < gc; j++) r += (gat[j] > x);
                    if (r == kk - 1) sh_thr = x;
                }
                __syncthreads();
                return sh_thr;
            } else {
                k = kk;
                shift = (shift >= 11) ? shift - 11 : 0;
                __syncthreads();
            }
        }
    };

    // ---- phase 0: thrA = 64th-largest keyA among positives (only if npos > 64)
    ull thrA = 0;
    if (npos > NFG) {
        thrA = radix([&](uint32_t j, bool& e) -> ull {
            ull ent = posEnt(j, e); return keyA_of(ent); }, mPos, NFG, 26);
    }

    // exact jnp prio keys: f32 bits of (cls + r), rounding included
    auto keyB_pos = [&](ull ent) -> ull {
        uint32_t mant = (uint32_t)((ent >> 21) & 0x7FFFFFull);
        uint32_t invn = (uint32_t)((ent >> 7) & 0x3FFFull);
        float r = __uint_as_float(0x3F800000u | mant) - 1.0f;
        uint32_t cls = (keyA_of(ent) >= thrA) ? 3u : 1u;
        float prio = (float)cls + r;
        return (((ull)__float_as_uint(prio)) << 14) | (ull)invn;
    };
    auto keyB_neg = [](ull ent) -> ull {
        uint32_t mant = (uint32_t)((ent >> 21) & 0x7FFFFFull);
        uint32_t invn = (uint32_t)((ent >> 7) & 0x3FFFull);
        float r = __uint_as_float(0x3F800000u | mant) - 1.0f;
        float prio = 2.0f + r;
        return (((ull)__float_as_uint(prio)) << 14) | (ull)invn;
    };
    auto keyB_ign = [](ull ent) -> ull {
        uint32_t mant = (uint32_t)((ent >> 21) & 0x7FFFFFull);
        uint32_t invn = (uint32_t)((ent >> 7) & 0x3FFFull);
        float r = __uint_as_float(0x3F800000u | mant) - 1.0f;
        float prio = 0.0f + r;
        return (((ull)__float_as_uint(prio)) << 14) | (ull)invn;
    };

    // ---- phase 1: threshold for the 256-cut (boundary class analytic)
    const uint32_t c3 = (npos < NFG) ? npos : NFG;
    const uint32_t c2 = nneg;
    uint32_t clsStar = (npn >= NSAMP) ? ((NSAMP <= c3 + c2) ? 2u : 1u) : 0u;
    bool scanL = true;
    const bool scanI = (clsStar == 0u);
    ull thrB = 0;
    if (clsStar == 2u) {
        uint32_t k2 = NSAMP - c3;
        if (nH >= k2) {     // usual: top negatives all in the high slab
            scanL = false;  // negL keys provably < any negH key (strict sep at NEGT)
            thrB = radix([&](uint32_t j, bool& e) -> ull {
                ull ent = nhEnt(j, e); return keyB_neg(ent); }, mH, k2, 26);
        } else {            // fallback: virtual concat negH ++ negL (masked segmented)
            thrB = radix([&](uint32_t j, bool& e) -> ull {
                if (j < mH) { ull ent = nhEnt(j, e); return keyB_neg(ent); }
                ull ent = nlEnt(j - mH, e); return keyB_neg(ent); },
                mH + MSEG, k2, 26);
        }
    } else if (clsStar == 1u) {
        thrB = radix([&](uint32_t j, bool& e) -> ull {
            ull ent = posEnt(j, e);
            ull kb = keyB_pos(ent);
            e = e && ((kb >> 14) < 0x40000000ull);   // cls1 only (prio < 2.0)
            return kb; }, mPos, NSAMP - c3 - c2, 26);
    } else {
        thrB = radix([&](uint32_t j, bool& e) -> ull {
            ull ent = igEnt(j, e); return keyB_ign(ent); }, MSEG, NSAMP - npn, 34);
    }
    __syncthreads();

    // ---- compact: exactly NSAMP keys (keys unique)
    auto push = [&](ull key, ull ent, uint32_t fg) {
        uint32_t s = atomicAdd(&selc, 1u);
        if (s < NSAMP) { selk[s] = key; sela[s] = (fg << 7) | (uint32_t)(ent & 0x7Full); }
    };
    for (uint32_t j = tid; j < mPos; j += 1024) {
        bool e; ull ent = posEnt(j, e);
        if (!e) continue;
        ull key = keyB_pos(ent);
        if (clsStar == 0u || key >= thrB) push(key, ent, 1u);
    }
    for (uint32_t j = tid; j < mH; j += 1024) {
        bool e; ull ent = nhEnt(j, e);
        if (!e) continue;
        ull key = keyB_neg(ent);
        if (clsStar == 0u || key >= thrB) push(key, ent, 0u);
    }
    if (scanL) {
        for (uint32_t j = tid; j < MSEG; j += 1024) {
            bool e; ull ent = nlEnt(j, e);
            if (!e) continue;
            ull key = keyB_neg(ent);
            if (clsStar == 0u || key >= thrB) push(key, ent, 0u);
        }
    }
    if (scanI) {
        for (uint32_t j = tid; j < MSEG; j += 1024) {
            bool e; ull ent = igEnt(j, e);
            if (!e) continue;
            ull key = keyB_ign(ent);
            if (key >= thrB) push(key, ent, 0u);
        }
    }
    __syncthreads();

    // ---- rank-scatter: output row = count of greater keys (desc sort position)
    if (tid < NSAMP) {
        ull x = selk[tid];
        uint32_t r = 0;
        for (int j = 0; j < NSAMP; j++) r += (selk[j] > x);
        uint32_t n = 16383u - (uint32_t)(x & 0x3FFFull);
        uint32_t aux = sela[tid];
        uint32_t bg = aux & 0x7Fu;
        const int isfg = (int)((aux >> 7) & 1u);
        const float4 pb = ((const float4*)props)[(size_t)b * NPROP + n];
        const float4 gb = ((const float4*)gts)[(size_t)b * NGT + bg];
        const size_t O_ROI = 0;
        const size_t O_LBL = (size_t)BATCH * NSAMP * 4;
        const size_t O_TGT = O_LBL + (size_t)BATCH * NSAMP;
        const size_t O_INW = O_TGT + (size_t)BATCH * NSAMP * 4;
        const size_t O_OUW = O_INW + (size_t)BATCH * NSAMP * 4;
        const size_t row = (size_t)b * NSAMP + r;
        out[O_ROI + row * 4 + 0] = pb.x;
        out[O_ROI + row * 4 + 1] = pb.y;
        out[O_ROI + row * 4 + 2] = pb.z;
        out[O_ROI + row * 4 + 3] = pb.w;
        out[O_LBL + row] = isfg ? 1.0f : 0.0f;
        float rw  = pb.z - pb.x, rh = pb.w - pb.y;
        float gw  = gb.z - gb.x, gh = gb.w - gb.y;
        out[O_TGT + row * 4 + 0] = ((gb.x + gb.z) * 0.5f - (pb.x + pb.z) * 0.5f) / rw;
        out[O_TGT + row * 4 + 1] = ((gb.y + gb.w) * 0.5f - (pb.y + pb.w) * 0.5f) / rh;
        out[O_TGT + row * 4 + 2] = logf(gw / rw);
        out[O_TGT + row * 4 + 3] = logf(gh / rh);
        float wv = isfg ? 1.0f : 0.0f;
        for (int c = 0; c < 4; c++) {
            out[O_INW + row * 4 + c] = wv;
            out[O_OUW + row * 4 + c] = wv;
        }
    }
}

extern "C" void kernel_launch(void* const* d_in, const int* in_sizes, int n_in,
                              void* d_out, int out_size, void* d_ws, size_t ws_size,
                              hipStream_t stream) {
    (void)in_sizes; (void)n_in; (void)out_size; (void)ws_size;
    const float* props = (const float*)d_in[0];
    const float* gts   = (const float*)d_in[1];
    ull* lists = (ull*)d_ws;                                       // 16*4*16384*8 = 8 MB
    uint32_t* cntblk = (uint32_t*)((char*)d_ws + (size_t)BATCH * 4 * NPROP * 8); // 16 KB
    float* out = (float*)d_out;

    dim3 gridA(NBLK, BATCH);   // (64, 16), 256 threads: 1 proposal/lane (r0 form)
    k_compute<<<gridA, 256, 0, stream>>>(props, gts, lists, cntblk);
    k_select<<<BATCH, 1024, 0, stream>>>(props, gts, lists, cntblk, out);
}

// Round 9
// 99.078 us; speedup vs baseline: 1.2063x; 1.0341x over previous
//
#include <hip/hip_runtime.h>
#include <stdint.h>

#define BATCH 16
#define NPROP 16384
#define NGT   128
#define NSAMP 256
#define NFG   64
#define GCAP  512
#define PCAP  8192   // dense pos LDS cap (64 KB)
#define HCAP  4096   // dense neg LDS cap (32 KB)
#define NBLK  64     // segments (k_compute blocks) per batch
#define BPB   256    // proposals per segment
#define LOGB  8      // log2(BPB)

typedef unsigned long long ull;

// ---------- threefry2x32 block (key 0,1) ----------
__device__ __forceinline__ void thr_block(uint32_t c0, uint32_t c1,
                                          uint32_t* o0, uint32_t* o1) {
    const uint32_t k0 = 0u, k1 = 1u, ks2 = 0x1BD11BDBu; // 0^1^0x1BD11BDA
    uint32_t x0 = c0 + k0, x1 = c1 + k1;
#define RND(d) { x0 += x1; x1 = (x1 << d) | (x1 >> (32 - d)); x1 ^= x0; }
    RND(13) RND(15) RND(26) RND(6)   x0 += k1;  x1 += ks2 + 1u;
    RND(17) RND(29) RND(16) RND(24)  x0 += ks2; x1 += k0 + 2u;
    RND(13) RND(15) RND(26) RND(6)   x0 += k0;  x1 += k1 + 3u;
    RND(17) RND(29) RND(16) RND(24)  x0 += k1;  x1 += ks2 + 4u;
    RND(13) RND(15) RND(26) RND(6)   x0 += ks2; x1 += k0 + 5u;
#undef RND
    *o0 = x0; *o1 = x1;
}

__device__ __forceinline__ uint32_t thr_part_xor(uint32_t f) {
    uint32_t a, b; thr_block(0u, f, &a, &b);
    return a ^ b;
}

// list entry (u64): [44]=isPos, [43:21]=r mantissa (bits>>9), [20:7]=16383-n, [6:0]=argmax gt
// slabs per batch: 0=pos, 1=neg, 2=ign; entry at seg*BPB + local.
// cntblk[(b*NBLK+seg)*4 + cls] written NON-atomically every launch -> no zeroing kernel.
__global__ void __launch_bounds__(256) k_compute(
    const float* __restrict__ props, const float* __restrict__ gts,
    ull* __restrict__ lists, uint32_t* __restrict__ cntblk)
{
#pragma clang fp contract(off)
    const int b = blockIdx.y;
    const int blk = blockIdx.x;
    const int tid = threadIdx.x;
    const int n = blk * BPB + tid;         // 1 proposal per lane (r0-proven form)
    __shared__ float4 g4[NGT];
    __shared__ uint32_t wc[3][4], we_s[3][4];
    if (tid < NGT)
        g4[tid] = ((const float4*)gts)[(size_t)b * NGT + tid];
    __syncthreads();
    const float4 pb = ((const float4*)props)[(size_t)b * NPROP + n];
    const float ap = (pb.z - pb.x) * (pb.w - pb.y);
    float best = -1.0f; int bg = 0;
    #pragma unroll 4
    for (int i = 0; i < NGT; ++i) {
        const float4 gb = g4[i];            // wave-uniform broadcast read
        float ag = (gb.z - gb.x) * (gb.w - gb.y);
        float w  = fmaxf(fminf(pb.z, gb.z) - fmaxf(pb.x, gb.x), 0.0f);
        float hh = fmaxf(fminf(pb.w, gb.w) - fmaxf(pb.y, gb.y), 0.0f);
        float inter = w * hh;
        float un = fmaxf(ap + ag - inter, 1e-8f);
        float iou = inter / un;             // IEEE f32 div = numpy bits
        if (iou > best) { best = iou; bg = i; }   // first-max = argmax
    }
    uint32_t lab = (best >= 0.5f) ? 2u : ((best < 0.1f) ? 1u : 0u);
    const uint32_t f = (uint32_t)b * NPROP + (uint32_t)n;
    uint32_t mant = thr_part_xor(f) >> 9;
    ull entry = ((ull)(lab == 2u) << 44) | ((ull)mant << 21)
              | ((ull)(16383u - (uint32_t)n) << 7) | (ull)(uint32_t)bg;

    bool cP = (lab == 2u);
    bool cN = (lab == 1u);
    bool cI = (lab == 0u);
    ull mP = __ballot(cP), mN = __ballot(cN), mI = __ballot(cI);
    const int w = tid >> 6;
    const uint32_t lane = (uint32_t)tid & 63u;
    if (lane == 0) {
        wc[0][w] = (uint32_t)__popcll(mP);
        wc[1][w] = (uint32_t)__popcll(mN);
        wc[2][w] = (uint32_t)__popcll(mI);
    }
    __syncthreads();
    if (tid < 3) {       // per-seg NON-atomic counts: every slot written every launch
        uint32_t e = 0;
        #pragma unroll
        for (int i = 0; i < 4; i++) { we_s[tid][i] = e; e += wc[tid][i]; }
        cntblk[((size_t)b * NBLK + blk) * 4 + tid] = e;
    }
    __syncthreads();
    ull lt = lane ? (~0ull >> (64u - lane)) : 0ull;
    ull* slab = lists + (size_t)b * 4 * NPROP;
    const uint32_t segB = (uint32_t)blk * BPB;
    if (cP) slab[0 * NPROP + segB + we_s[0][w] + (uint32_t)__popcll(mP & lt)] = entry;
    if (cN) slab[1 * NPROP + segB + we_s[1][w] + (uint32_t)__popcll(mN & lt)] = entry;
    if (cI) slab[2 * NPROP + segB + we_s[2][w] + (uint32_t)__popcll(mI & lt)] = entry;
}

__global__ void __launch_bounds__(1024) k_select(
    const float* __restrict__ props, const float* __restrict__ gts,
    const ull* __restrict__ lists, const uint32_t* __restrict__ cntblk,
    float* __restrict__ out)
{
#pragma clang fp contract(off)
    const int b = blockIdx.x;
    const int tid = threadIdx.x;
    const int wid = tid >> 6;
    const uint32_t lane = (uint32_t)tid & 63u;
    __shared__ ull      dpos[PCAP];      // 64 KB dense pos
    __shared__ ull      dneg[HCAP];      // 32 KB dense neg
    __shared__ uint32_t histA[2048];     // 8 KB
    __shared__ uint32_t histB[2048];     // 8 KB
    __shared__ ull      gatA[GCAP];      // 4 KB (serial path reuses as gat)
    __shared__ ull      gatB[GCAP];      // 4 KB
    __shared__ ull      selk[NSAMP];     // 2 KB
    __shared__ uint32_t sela[NSAMP];     // 1 KB
    __shared__ uint32_t bc[NBLK * 4];    // 1 KB per-seg counts
    __shared__ uint32_t preP[NBLK], preN[NBLK], tot[3];
    __shared__ uint32_t shA[3], shB[3], shS[3];   // (dig, k-in-bucket, cnt-in-bucket)
    __shared__ uint32_t gcA, gcB, gcnt, selc;
    __shared__ ull sh_thrA, sh_thrB, sh_thr;

    const ull* Spos = lists + ((size_t)b * 4 + 0) * NPROP;
    const ull* Sneg = lists + ((size_t)b * 4 + 1) * NPROP;
    const ull* Sign = lists + ((size_t)b * 4 + 2) * NPROP;

    // ---- S1: load counts, zero hists, per-class prefix scans + totals
    if (tid < NBLK * 4) bc[tid] = cntblk[(size_t)b * NBLK * 4 + tid];
    histA[tid] = 0; histA[tid + 1024] = 0;
    histB[tid] = 0; histB[tid + 1024] = 0;
    if (tid == 0) { gcA = 0; gcB = 0; gcnt = 0; selc = 0; }
    __syncthreads();
    if (wid < 3) {      // wave w scans class w over 64 segments (shuffle scan)
        uint32_t own = bc[lane * 4 + (uint32_t)wid];
        uint32_t v = own;
        #pragma unroll
        for (int off = 1; off < 64; off <<= 1) {
            uint32_t t = (uint32_t)__shfl_up((int)v, off);
            if (lane >= (uint32_t)off) v += t;
        }
        if (wid == 0) preP[lane] = v - own;
        else if (wid == 1) preN[lane] = v - own;
        if (lane == 63) tot[wid] = v;
    }
    __syncthreads();
    const uint32_t npos = tot[0], nneg = tot[1], nig = tot[2];
    const uint32_t npn  = npos + nneg;
    const uint32_t c3   = (npos < NFG) ? npos : NFG;
    const uint32_t k2   = NSAMP - c3;
    const bool dP = (npos <= PCAP), dH = (nneg <= HCAP);
    const bool fast0 = (npn >= NSAMP) && (c3 + nneg >= NSAMP) && dP && dH;

    auto keyA_of = [](ull e) -> ull {    // raw (mant, invn): jnp stable argsort on r
        return (((e >> 21) & 0x7FFFFFull) << 14) | ((e >> 7) & 0x3FFFull);
    };
    auto keyB_neg = [](ull ent) -> ull { // exact f32 bits of (2 + r), RNE included
        uint32_t mant = (uint32_t)((ent >> 21) & 0x7FFFFFull);
        uint32_t invn = (uint32_t)((ent >> 7) & 0x3FFFull);
        float r = __uint_as_float(0x3F800000u | mant) - 1.0f;
        float prio = 2.0f + r;
        return (((ull)__float_as_uint(prio)) << 14) | (ull)invn;
    };
    auto keyB_ign = [](ull ent) -> ull {
        uint32_t mant = (uint32_t)((ent >> 21) & 0x7FFFFFull);
        uint32_t invn = (uint32_t)((ent >> 7) & 0x3FFFull);
        float r = __uint_as_float(0x3F800000u | mant) - 1.0f;
        float prio = 0.0f + r;
        return (((ull)__float_as_uint(prio)) << 14) | (ull)invn;
    };
    ull thrA = 0;                        // captured by keyB_pos (serial + compact)
    auto keyB_pos = [&](ull ent) -> ull {
        uint32_t mant = (uint32_t)((ent >> 21) & 0x7FFFFFull);
        uint32_t invn = (uint32_t)((ent >> 7) & 0x3FFFull);
        float r = __uint_as_float(0x3F800000u | mant) - 1.0f;
        uint32_t cls = (keyA_of(ent) >= thrA) ? 3u : 1u;
        float prio = (float)cls + r;
        return (((ull)__float_as_uint(prio)) << 14) | (ull)invn;
    };
    auto push = [&](ull key, ull ent, uint32_t fg) {
        uint32_t s = atomicAdd(&selc, 1u);
        if (s < NSAMP) { selk[s] = key; sela[s] = (fg << 7) | (uint32_t)(ent & 0x7Full); }
    };

    // ---- S2: prefix-based staging (no atomic chains) + both histograms
    for (int s4 = 0; s4 < 4; ++s4) {
        uint32_t seg = (uint32_t)(wid * 4 + s4);
        if (dP) {
            uint32_t c = bc[seg * 4 + 0], bb = preP[seg];
            for (uint32_t i = lane; i < c; i += 64) {
                ull ent = Spos[seg * BPB + i];
                dpos[bb + i] = ent;
                if (fast0 && npos > NFG)
                    atomicAdd(&histA[(uint32_t)(keyA_of(ent) >> 26) & 2047u], 1u);
            }
        }
        if (dH) {
            uint32_t c = bc[seg * 4 + 1], bb = preN[seg];
            for (uint32_t i = lane; i < c; i += 64) {
                ull ent = Sneg[seg * BPB + i];
                dneg[bb + i] = ent;
                if (fast0)
                    atomicAdd(&histB[(uint32_t)(keyB_neg(ent) >> 26) & 2047u], 1u);
            }
        }
    }
    __syncthreads();

    // per-wave boundary locate over 2048 monotone bins (suffix-scan, rotated reads)
    auto locW = [&](const uint32_t* h, uint32_t k, uint32_t* o3) {
        uint32_t cs = 0;
        if (lane < 32) {
            const uint32_t base = lane * 64u;
            #pragma unroll 8
            for (uint32_t i = 0; i < 64; i++) cs += h[base + ((i + lane) & 63u)];
        }
        uint32_t s = cs;
        #pragma unroll
        for (int off = 1; off < 32; off <<= 1) {
            uint32_t t = __shfl_down(s, off);
            if (lane + off < 32) s += t;
        }
        uint32_t sExcl = s - cs;
        bool cond = (lane < 32) && (sExcl < k) && (k <= s);
        ull ball = __ballot(cond);
        uint32_t cstar = (uint32_t)(__ffsll((unsigned long long)ball) - 1);
        uint32_t kc_ = (uint32_t)__shfl((int)(k - sExcl), (int)cstar);
        uint32_t val = h[cstar * 64u + lane];
        uint32_t fi = val;
        #pragma unroll
        for (int off = 1; off < 64; off <<= 1) {
            uint32_t t = __shfl_down(fi, off);
            if (lane + off < 64) fi += t;
        }
        uint32_t fExcl = fi - val;
        bool cond2 = (fExcl < kc_) && (kc_ <= fi);
        ull ball2 = __ballot(cond2);
        uint32_t bstar = (uint32_t)(__ffsll((unsigned long long)ball2) - 1);
        if (lane == bstar) { o3[0] = cstar * 64u + lane; o3[1] = kc_ - fExcl; o3[2] = val; }
    };

    bool fast = fast0;
    if (fast) {
        // ---- S3: locate A (wave0) and B (wave1) concurrently
        if (wid == 0 && npos > NFG) locW(histA, NFG, shA);
        if (wid == 1)               locW(histB, k2,  shB);
        __syncthreads();
        if ((npos > NFG && shA[2] > GCAP) || (shB[2] > GCAP)) fast = false; // uniform
    }
    if (fast) {
        // ---- S4: fused gather (pos bucket -> gatA, neg bucket -> gatB)
        if (npos > NFG) {
            uint32_t digA = shA[0];
            for (uint32_t j = tid; j < npos; j += 1024) {
                ull k = keyA_of(dpos[j]);
                if (((uint32_t)(k >> 26) & 2047u) == digA) gatA[atomicAdd(&gcA, 1u)] = k;
            }
        }
        {
            uint32_t digB = shB[0];
            for (uint32_t j = tid; j < nneg; j += 1024) {
                ull k = keyB_neg(dneg[j]);
                if (((uint32_t)(k >> 26) & 2047u) == digB) gatB[atomicAdd(&gcB, 1u)] = k;
            }
        }
        __syncthreads();
        // ---- S5: concurrent rank-selects (A on tids<512, B on tids>=512)
        if (npos > NFG) {
            if ((uint32_t)tid < gcA) {
                ull x = gatA[tid]; uint32_t r = 0;
                for (uint32_t j = 0; j < gcA; j++) r += (gatA[j] > x);
                if (r == shA[1] - 1) sh_thrA = x;
            }
        } else if (tid == 0) sh_thrA = 0;
        if (tid >= 512 && (uint32_t)(tid - 512) < gcB) {
            ull x = gatB[tid - 512]; uint32_t r = 0;
            for (uint32_t j = 0; j < gcB; j++) r += (gatB[j] > x);
            if (r == shB[1] - 1) sh_thrB = x;
        }
        __syncthreads();
        thrA = sh_thrA;
        const ull thrB = sh_thrB;
        // ---- S6: compact (exactly c3 + k2 = 256; keys unique)
        for (uint32_t j = tid; j < npos; j += 1024) {
            ull ent = dpos[j];
            if (keyA_of(ent) >= thrA) push(keyB_pos(ent), ent, 1u);
        }
        for (uint32_t j = tid; j < nneg; j += 1024) {
            ull ent = dneg[j];
            ull k = keyB_neg(ent);
            if (k >= thrB) push(k, ent, 0u);
        }
        __syncthreads();
    }
    if (!fast) {
        // ================= serial fallback: r8-verified radix pipeline ==========
        const uint32_t MSEG = NBLK * BPB;
        const uint32_t mPos = dP ? npos : MSEG;
        const uint32_t mNeg = dH ? nneg : MSEG;
        auto posEnt = [&](uint32_t j, bool& e) -> ull {
            if (dP) { e = true; return dpos[j]; }
            e = (j & (BPB - 1u)) < bc[(j >> LOGB) * 4 + 0];
            return e ? Spos[j] : 0ull;
        };
        auto negEnt = [&](uint32_t j, bool& e) -> ull {
            if (dH) { e = true; return dneg[j]; }
            e = (j & (BPB - 1u)) < bc[(j >> LOGB) * 4 + 1];
            return e ? Sneg[j] : 0ull;
        };
        auto igEnt = [&](uint32_t j, bool& e) -> ull {
            e = (j & (BPB - 1u)) < bc[(j >> LOGB) * 4 + 2];
            return e ? Sign[j] : 0ull;
        };
        auto radix = [&](auto&& kf, uint32_t m, uint32_t k, int shift) -> ull {
            if (m <= GCAP) {   // direct: gather all eligible, rank-select
                if (tid == 0) gcnt = 0;
                __syncthreads();
                for (uint32_t j = tid; j < m; j += 1024) {
                    bool e; ull key = kf(j, e);
                    if (e) { uint32_t s = atomicAdd(&gcnt, 1u); gatA[s] = key; }
                }
                __syncthreads();
                uint32_t gc = gcnt;
                if ((uint32_t)tid < gc) {
                    ull x = gatA[tid]; uint32_t r = 0;
                    for (uint32_t j = 0; j < gc; j++) r += (gatA[j] > x);
                    if (r == k - 1) sh_thr = x;
                }
                __syncthreads();
                return sh_thr;
            }
            ull prefix = 0, mask = 0;
            for (;;) {
                histA[tid] = 0; histA[tid + 1024] = 0;
                __syncthreads();
                for (uint32_t j = tid; j < m; j += 1024) {
                    bool e; ull key = kf(j, e);
                    if (e && ((key ^ prefix) & mask) == 0)
                        atomicAdd(&histA[(uint32_t)(key >> shift) & 2047u], 1u);
                }
                __syncthreads();
                if (tid < 64) locW(histA, k, shS);
                __syncthreads();
                uint32_t dig = shS[0], kk = shS[1], cnt = shS[2];
                prefix |= ((ull)dig) << shift;
                mask   |= 2047ull << shift;
                if (cnt <= GCAP || shift == 0) {
                    if (tid == 0) gcnt = 0;
                    __syncthreads();
                    for (uint32_t j = tid; j < m; j += 1024) {
                        bool e; ull key = kf(j, e);
                        if (e && ((key ^ prefix) & mask) == 0) {
                            uint32_t s = atomicAdd(&gcnt, 1u);
                            if (s < GCAP) gatA[s] = key;
                        }
                    }
                    __syncthreads();
                    uint32_t gc = (gcnt < GCAP) ? gcnt : GCAP;
                    if ((uint32_t)tid < gc) {
                        ull x = gatA[tid]; uint32_t r = 0;
                        for (uint32_t j = 0; j < gc; j++) r += (gatA[j] > x);
                        if (r == kk - 1) sh_thr = x;
                    }
                    __syncthreads();
                    return sh_thr;
                } else {
                    k = kk;
                    shift = (shift >= 11) ? shift - 11 : 0;
                    __syncthreads();
                }
            }
        };

        // phase 0: thrA = 64th-largest keyA among positives (only if npos > 64)
        if (npos > NFG) {
            thrA = radix([&](uint32_t j, bool& e) -> ull {
                ull ent = posEnt(j, e); return keyA_of(ent); }, mPos, NFG, 26);
        }
        // phase 1: boundary class analytic
        uint32_t clsStar = (npn >= NSAMP) ? ((NSAMP <= c3 + nneg) ? 2u : 1u) : 0u;
        ull thrB = 0;
        if (clsStar == 2u) {
            thrB = radix([&](uint32_t j, bool& e) -> ull {
                ull ent = negEnt(j, e); return keyB_neg(ent); }, mNeg, k2, 26);
        } else if (clsStar == 1u) {
            thrB = radix([&](uint32_t j, bool& e) -> ull {
                ull ent = posEnt(j, e);
                ull kb = keyB_pos(ent);
                e = e && ((kb >> 14) < 0x40000000ull);   // cls1 only (prio < 2.0)
                return kb; }, mPos, NSAMP - c3 - nneg, 26);
        } else {
            thrB = radix([&](uint32_t j, bool& e) -> ull {
                ull ent = igEnt(j, e); return keyB_ign(ent); }, MSEG, NSAMP - npn, 34);
        }
        __syncthreads();
        // compact
        for (uint32_t j = tid; j < mPos; j += 1024) {
            bool e; ull ent = posEnt(j, e);
            if (!e) continue;
            ull key = keyB_pos(ent);
            if (clsStar == 0u || key >= thrB) push(key, ent, 1u);
        }
        for (uint32_t j = tid; j < mNeg; j += 1024) {
            bool e; ull ent = negEnt(j, e);
            if (!e) continue;
            ull key = keyB_neg(ent);
            if (clsStar == 0u || key >= thrB) push(key, ent, 0u);
        }
        if (clsStar == 0u) {
            for (uint32_t j = tid; j < MSEG; j += 1024) {
                bool e; ull ent = igEnt(j, e);
                if (!e) continue;
                ull key = keyB_ign(ent);
                if (key >= thrB) push(key, ent, 0u);
            }
        }
        __syncthreads();
    }

    // ---- S7: rank-scatter: output row = count of greater keys (desc sort position)
    if (tid < NSAMP) {
        ull x = selk[tid];
        uint32_t r = 0;
        for (int j = 0; j < NSAMP; j++) r += (selk[j] > x);
        uint32_t n = 16383u - (uint32_t)(x & 0x3FFFull);
        uint32_t aux = sela[tid];
        uint32_t bg = aux & 0x7Fu;
        const int isfg = (int)((aux >> 7) & 1u);
        const float4 pb = ((const float4*)props)[(size_t)b * NPROP + n];
        const float4 gb = ((const float4*)gts)[(size_t)b * NGT + bg];
        const size_t O_ROI = 0;
        const size_t O_LBL = (size_t)BATCH * NSAMP * 4;
        const size_t O_TGT = O_LBL + (size_t)BATCH * NSAMP;
        const size_t O_INW = O_TGT + (size_t)BATCH * NSAMP * 4;
        const size_t O_OUW = O_INW + (size_t)BATCH * NSAMP * 4;
        const size_t row = (size_t)b * NSAMP + r;
        out[O_ROI + row * 4 + 0] = pb.x;
        out[O_ROI + row * 4 + 1] = pb.y;
        out[O_ROI + row * 4 + 2] = pb.z;
        out[O_ROI + row * 4 + 3] = pb.w;
        out[O_LBL + row] = isfg ? 1.0f : 0.0f;
        float rw  = pb.z - pb.x, rh = pb.w - pb.y;
        float gw  = gb.z - gb.x, gh = gb.w - gb.y;
        out[O_TGT + row * 4 + 0] = ((gb.x + gb.z) * 0.5f - (pb.x + pb.z) * 0.5f) / rw;
        out[O_TGT + row * 4 + 1] = ((gb.y + gb.w) * 0.5f - (pb.y + pb.w) * 0.5f) / rh;
        out[O_TGT + row * 4 + 2] = logf(gw / rw);
        out[O_TGT + row * 4 + 3] = logf(gh / rh);
        float wv = isfg ? 1.0f : 0.0f;
        for (int c = 0; c < 4; c++) {
            out[O_INW + row * 4 + c] = wv;
            out[O_OUW + row * 4 + c] = wv;
        }
    }
}

extern "C" void kernel_launch(void* const* d_in, const int* in_sizes, int n_in,
                              void* d_out, int out_size, void* d_ws, size_t ws_size,
                              hipStream_t stream) {
    (void)in_sizes; (void)n_in; (void)out_size; (void)ws_size;
    const float* props = (const float*)d_in[0];
    const float* gts   = (const float*)d_in[1];
    ull* lists = (ull*)d_ws;                                       // 16*4*16384*8 = 8 MB
    uint32_t* cntblk = (uint32_t*)((char*)d_ws + (size_t)BATCH * 4 * NPROP * 8); // 16 KB
    float* out = (float*)d_out;

    dim3 gridA(NBLK, BATCH);   // (64, 16), 256 threads: 1 proposal/lane
    k_compute<<<gridA, 256, 0, stream>>>(props, gts, lists, cntblk);
    k_select<<<BATCH, 1024, 0, stream>>>(props, gts, lists, cntblk, out);
}

// Round 10
// 97.815 us; speedup vs baseline: 1.2219x; 1.0129x over previous
//
#include <hip/hip_runtime.h>
#include <stdint.h>

#define BATCH 16
#define NPROP 16384
#define NGT   128
#define NSAMP 256
#define NFG   64
#define GCAP  512
#define PCAP  8192   // dense pos LDS cap (64 KB)
#define HCAP  2048   // dense negH LDS cap (16 KB)
#define NBLK  64     // segments (k_compute blocks) per batch
#define BPB   256    // proposals per segment
#define LOGB  8      // log2(BPB)
#define NEGT  0x780002u  // neg high/low mant split; strict f32(2+r) separation (RNE)

typedef unsigned long long ull;

// ---------- threefry2x32 block (key 0,1) ----------
__device__ __forceinline__ void thr_block(uint32_t c0, uint32_t c1,
                                          uint32_t* o0, uint32_t* o1) {
    const uint32_t k0 = 0u, k1 = 1u, ks2 = 0x1BD11BDBu; // 0^1^0x1BD11BDA
    uint32_t x0 = c0 + k0, x1 = c1 + k1;
#define RND(d) { x0 += x1; x1 = (x1 << d) | (x1 >> (32 - d)); x1 ^= x0; }
    RND(13) RND(15) RND(26) RND(6)   x0 += k1;  x1 += ks2 + 1u;
    RND(17) RND(29) RND(16) RND(24)  x0 += ks2; x1 += k0 + 2u;
    RND(13) RND(15) RND(26) RND(6)   x0 += k0;  x1 += k1 + 3u;
    RND(17) RND(29) RND(16) RND(24)  x0 += k1;  x1 += ks2 + 4u;
    RND(13) RND(15) RND(26) RND(6)   x0 += ks2; x1 += k0 + 5u;
#undef RND
    *o0 = x0; *o1 = x1;
}

__device__ __forceinline__ uint32_t thr_part_xor(uint32_t f) {
    uint32_t a, b; thr_block(0u, f, &a, &b);
    return a ^ b;
}

// list entry (u64): [44]=isPos, [43:21]=r mantissa (bits>>9), [20:7]=16383-n, [6:0]=argmax gt
// slabs per batch: 0=pos, 1=negH (mant>=NEGT), 2=negL, 3=ign; entry at seg*BPB + local.
// cntblk[(b*NBLK+seg)*4 + cls] written NON-atomically every launch -> no zeroing kernel.
__global__ void __launch_bounds__(256) k_compute(
    const float* __restrict__ props, const float* __restrict__ gts,
    ull* __restrict__ lists, uint32_t* __restrict__ cntblk)
{
#pragma clang fp contract(off)
    const int b = blockIdx.y;
    const int blk = blockIdx.x;
    const int tid = threadIdx.x;
    const int n = blk * BPB + tid;         // 1 proposal per lane (r0-proven form)
    __shared__ float4 g4[NGT];
    __shared__ uint32_t wc[4][4], we_s[4][4];
    if (tid < NGT)
        g4[tid] = ((const float4*)gts)[(size_t)b * NGT + tid];
    __syncthreads();
    const float4 pb = ((const float4*)props)[(size_t)b * NPROP + n];
    const float ap = (pb.z - pb.x) * (pb.w - pb.y);
    float best = -1.0f; int bg = 0;
    #pragma unroll 4
    for (int i = 0; i < NGT; ++i) {
        const float4 gb = g4[i];            // wave-uniform broadcast read
        float ag = (gb.z - gb.x) * (gb.w - gb.y);
        float w  = fmaxf(fminf(pb.z, gb.z) - fmaxf(pb.x, gb.x), 0.0f);
        float hh = fmaxf(fminf(pb.w, gb.w) - fmaxf(pb.y, gb.y), 0.0f);
        float inter = w * hh;
        float un = fmaxf(ap + ag - inter, 1e-8f);
        float iou = inter / un;             // IEEE f32 div = numpy bits
        if (iou > best) { best = iou; bg = i; }   // first-max = argmax
    }
    uint32_t lab = (best >= 0.5f) ? 2u : ((best < 0.1f) ? 1u : 0u);
    const uint32_t f = (uint32_t)b * NPROP + (uint32_t)n;
    uint32_t mant = thr_part_xor(f) >> 9;
    ull entry = ((ull)(lab == 2u) << 44) | ((ull)mant << 21)
              | ((ull)(16383u - (uint32_t)n) << 7) | (ull)(uint32_t)bg;

    bool cP = (lab == 2u);
    bool cH = (lab == 1u) && (mant >= NEGT);
    bool cL = (lab == 1u) && (mant <  NEGT);
    bool cI = (lab == 0u);
    ull mP = __ballot(cP), mH = __ballot(cH), mL = __ballot(cL), mI = __ballot(cI);
    const int w = tid >> 6;
    const uint32_t lane = (uint32_t)tid & 63u;
    if (lane == 0) {
        wc[0][w] = (uint32_t)__popcll(mP);
        wc[1][w] = (uint32_t)__popcll(mH);
        wc[2][w] = (uint32_t)__popcll(mL);
        wc[3][w] = (uint32_t)__popcll(mI);
    }
    __syncthreads();
    if (tid < 4) {       // per-seg NON-atomic counts: every slot written every launch
        uint32_t e = 0;
        #pragma unroll
        for (int i = 0; i < 4; i++) { we_s[tid][i] = e; e += wc[tid][i]; }
        cntblk[((size_t)b * NBLK + blk) * 4 + tid] = e;
    }
    __syncthreads();
    ull lt = lane ? (~0ull >> (64u - lane)) : 0ull;
    ull* slab = lists + (size_t)b * 4 * NPROP;
    const uint32_t segB = (uint32_t)blk * BPB;
    if (cP) slab[0 * NPROP + segB + we_s[0][w] + (uint32_t)__popcll(mP & lt)] = entry;
    if (cH) slab[1 * NPROP + segB + we_s[1][w] + (uint32_t)__popcll(mH & lt)] = entry;
    if (cL) slab[2 * NPROP + segB + we_s[2][w] + (uint32_t)__popcll(mL & lt)] = entry;
    if (cI) slab[3 * NPROP + segB + we_s[3][w] + (uint32_t)__popcll(mI & lt)] = entry;
}

__global__ void __launch_bounds__(1024) k_select(
    const float* __restrict__ props, const float* __restrict__ gts,
    const ull* __restrict__ lists, const uint32_t* __restrict__ cntblk,
    float* __restrict__ out)
{
#pragma clang fp contract(off)
    const int b = blockIdx.x;
    const int tid = threadIdx.x;
    const int wid = tid >> 6;
    const uint32_t lane = (uint32_t)tid & 63u;
    __shared__ ull      dpos[PCAP];      // 64 KB dense pos
    __shared__ ull      dnh[HCAP];       // 16 KB dense negH
    __shared__ uint32_t histA[2048];     // 8 KB
    __shared__ uint32_t histB[2048];     // 8 KB
    __shared__ ull      gatA[GCAP];      // 4 KB (serial path reuses as gat)
    __shared__ ull      gatB[GCAP];      // 4 KB
    __shared__ ull      selk[NSAMP];     // 2 KB
    __shared__ uint32_t sela[NSAMP];     // 1 KB
    __shared__ uint32_t bc[NBLK * 4];    // 1 KB per-seg counts
    __shared__ uint32_t preP[NBLK], preH[NBLK], tot[4];
    __shared__ uint32_t shA[3], shB[3], shS[3];   // (dig, k-in-bucket, cnt-in-bucket)
    __shared__ uint32_t gcA, gcB, gcnt, selc;
    __shared__ ull sh_thrA, sh_thrB, sh_thr;

    const ull* Spos = lists + ((size_t)b * 4 + 0) * NPROP;
    const ull* SnH  = lists + ((size_t)b * 4 + 1) * NPROP;
    const ull* SnL  = lists + ((size_t)b * 4 + 2) * NPROP;
    const ull* Sign = lists + ((size_t)b * 4 + 3) * NPROP;

    // ---- S1: load counts, zero hists, per-class prefix scans + totals
    if (tid < NBLK * 4) bc[tid] = cntblk[(size_t)b * NBLK * 4 + tid];
    histA[tid] = 0; histA[tid + 1024] = 0;
    histB[tid] = 0; histB[tid + 1024] = 0;
    if (tid == 0) { gcA = 0; gcB = 0; gcnt = 0; selc = 0; }
    __syncthreads();
    if (wid < 4) {      // wave w scans class w over 64 segments (shuffle scan)
        uint32_t own = bc[lane * 4 + (uint32_t)wid];
        uint32_t v = own;
        #pragma unroll
        for (int off = 1; off < 64; off <<= 1) {
            uint32_t t = (uint32_t)__shfl_up((int)v, off);
            if (lane >= (uint32_t)off) v += t;
        }
        if (wid == 0) preP[lane] = v - own;
        else if (wid == 1) preH[lane] = v - own;
        if (lane == 63) tot[wid] = v;
    }
    __syncthreads();
    const uint32_t npos = tot[0], nH = tot[1], nL = tot[2], nig = tot[3];
    const uint32_t nneg = nH + nL;
    const uint32_t npn  = npos + nneg;
    const uint32_t c3   = (npos < NFG) ? npos : NFG;
    const uint32_t k2   = NSAMP - c3;
    const bool dP = (npos <= PCAP), dH = (nH <= HCAP);
    // fast path: cut falls in class 2, and negH alone covers it (strict NEGT sep)
    const bool fast0 = (npn >= NSAMP) && (c3 + nneg >= NSAMP) && dP && dH && (nH >= k2);

    auto keyA_of = [](ull e) -> ull {    // raw (mant, invn): jnp stable argsort on r
        return (((e >> 21) & 0x7FFFFFull) << 14) | ((e >> 7) & 0x3FFFull);
    };
    auto keyB_neg = [](ull ent) -> ull { // exact f32 bits of (2 + r), RNE included
        uint32_t mant = (uint32_t)((ent >> 21) & 0x7FFFFFull);
        uint32_t invn = (uint32_t)((ent >> 7) & 0x3FFFull);
        float r = __uint_as_float(0x3F800000u | mant) - 1.0f;
        float prio = 2.0f + r;
        return (((ull)__float_as_uint(prio)) << 14) | (ull)invn;
    };
    auto keyB_ign = [](ull ent) -> ull {
        uint32_t mant = (uint32_t)((ent >> 21) & 0x7FFFFFull);
        uint32_t invn = (uint32_t)((ent >> 7) & 0x3FFFull);
        float r = __uint_as_float(0x3F800000u | mant) - 1.0f;
        float prio = 0.0f + r;
        return (((ull)__float_as_uint(prio)) << 14) | (ull)invn;
    };
    ull thrA = 0;                        // captured by keyB_pos (serial + compact)
    auto keyB_pos = [&](ull ent) -> ull {
        uint32_t mant = (uint32_t)((ent >> 21) & 0x7FFFFFull);
        uint32_t invn = (uint32_t)((ent >> 7) & 0x3FFFull);
        float r = __uint_as_float(0x3F800000u | mant) - 1.0f;
        uint32_t cls = (keyA_of(ent) >= thrA) ? 3u : 1u;
        float prio = (float)cls + r;
        return (((ull)__float_as_uint(prio)) << 14) | (ull)invn;
    };
    auto push = [&](ull key, ull ent, uint32_t fg) {
        uint32_t s = atomicAdd(&selc, 1u);
        if (s < NSAMP) { selk[s] = key; sela[s] = (fg << 7) | (uint32_t)(ent & 0x7Full); }
    };

    // ---- S2: prefix-based staging (no atomic chains) + both histograms
    for (int s4 = 0; s4 < 4; ++s4) {
        uint32_t seg = (uint32_t)(wid * 4 + s4);
        if (dP) {
            uint32_t c = bc[seg * 4 + 0], bb = preP[seg];
            for (uint32_t i = lane; i < c; i += 64) {
                ull ent = Spos[seg * BPB + i];
                dpos[bb + i] = ent;
                if (fast0 && npos > NFG)
                    atomicAdd(&histA[(uint32_t)(keyA_of(ent) >> 26) & 2047u], 1u);
            }
        }
        if (dH) {
            uint32_t c = bc[seg * 4 + 1], bb = preH[seg];
            for (uint32_t i = lane; i < c; i += 64) {
                ull ent = SnH[seg * BPB + i];
                dnh[bb + i] = ent;
                if (fast0)
                    atomicAdd(&histB[(uint32_t)(keyB_neg(ent) >> 26) & 2047u], 1u);
            }
        }
    }
    __syncthreads();

    // per-wave boundary locate over 2048 monotone bins (suffix-scan, rotated reads)
    auto locW = [&](const uint32_t* h, uint32_t k, uint32_t* o3) {
        uint32_t cs = 0;
        if (lane < 32) {
            const uint32_t base = lane * 64u;
            #pragma unroll 8
            for (uint32_t i = 0; i < 64; i++) cs += h[base + ((i + lane) & 63u)];
        }
        uint32_t s = cs;
        #pragma unroll
        for (int off = 1; off < 32; off <<= 1) {
            uint32_t t = __shfl_down(s, off);
            if (lane + off < 32) s += t;
        }
        uint32_t sExcl = s - cs;
        bool cond = (lane < 32) && (sExcl < k) && (k <= s);
        ull ball = __ballot(cond);
        uint32_t cstar = (uint32_t)(__ffsll((unsigned long long)ball) - 1);
        uint32_t kc_ = (uint32_t)__shfl((int)(k - sExcl), (int)cstar);
        uint32_t val = h[cstar * 64u + lane];
        uint32_t fi = val;
        #pragma unroll
        for (int off = 1; off < 64; off <<= 1) {
            uint32_t t = __shfl_down(fi, off);
            if (lane + off < 64) fi += t;
        }
        uint32_t fExcl = fi - val;
        bool cond2 = (fExcl < kc_) && (kc_ <= fi);
        ull ball2 = __ballot(cond2);
        uint32_t bstar = (uint32_t)(__ffsll((unsigned long long)ball2) - 1);
        if (lane == bstar) { o3[0] = cstar * 64u + lane; o3[1] = kc_ - fExcl; o3[2] = val; }
    };

    bool fast = fast0;
    if (fast) {
        // ---- S3: locate A (wave0) and B (wave1) concurrently
        if (wid == 0 && npos > NFG) locW(histA, NFG, shA);
        if (wid == 1)               locW(histB, k2,  shB);
        __syncthreads();
        if ((npos > NFG && shA[2] > GCAP) || (shB[2] > GCAP)) fast = false; // uniform
    }
    if (fast) {
        // ---- S4: fused gather (pos bucket -> gatA, negH bucket -> gatB)
        if (npos > NFG) {
            uint32_t digA = shA[0];
            for (uint32_t j = tid; j < npos; j += 1024) {
                ull k = keyA_of(dpos[j]);
                if (((uint32_t)(k >> 26) & 2047u) == digA) gatA[atomicAdd(&gcA, 1u)] = k;
            }
        }
        {
            uint32_t digB = shB[0];
            for (uint32_t j = tid; j < nH; j += 1024) {
                ull k = keyB_neg(dnh[j]);
                if (((uint32_t)(k >> 26) & 2047u) == digB) gatB[atomicAdd(&gcB, 1u)] = k;
            }
        }
        __syncthreads();
        // ---- S5: concurrent rank-selects (A on tids<512, B on tids>=512)
        if (npos > NFG) {
            if ((uint32_t)tid < gcA) {
                ull x = gatA[tid]; uint32_t r = 0;
                for (uint32_t j = 0; j < gcA; j++) r += (gatA[j] > x);
                if (r == shA[1] - 1) sh_thrA = x;
            }
        } else if (tid == 0) sh_thrA = 0;
        if (tid >= 512 && (uint32_t)(tid - 512) < gcB) {
            ull x = gatB[tid - 512]; uint32_t r = 0;
            for (uint32_t j = 0; j < gcB; j++) r += (gatB[j] > x);
            if (r == shB[1] - 1) sh_thrB = x;
        }
        __syncthreads();
        thrA = sh_thrA;
        const ull thrB = sh_thrB;
        // ---- S6: compact (exactly c3 + k2 = 256; keys unique; negL/ign provably out)
        for (uint32_t j = tid; j < npos; j += 1024) {
            ull ent = dpos[j];
            if (keyA_of(ent) >= thrA) push(keyB_pos(ent), ent, 1u);
        }
        for (uint32_t j = tid; j < nH; j += 1024) {
            ull ent = dnh[j];
            ull k = keyB_neg(ent);
            if (k >= thrB) push(k, ent, 0u);
        }
        __syncthreads();
    }
    if (!fast) {
        // ================= serial fallback: r8-verified radix pipeline ==========
        const uint32_t MSEG = NBLK * BPB;
        const uint32_t mPos = dP ? npos : MSEG;
        const uint32_t mH   = dH ? nH   : MSEG;
        auto posEnt = [&](uint32_t j, bool& e) -> ull {
            if (dP) { e = true; return dpos[j]; }
            e = (j & (BPB - 1u)) < bc[(j >> LOGB) * 4 + 0];
            return e ? Spos[j] : 0ull;
        };
        auto nhEnt = [&](uint32_t j, bool& e) -> ull {
            if (dH) { e = true; return dnh[j]; }
            e = (j & (BPB - 1u)) < bc[(j >> LOGB) * 4 + 1];
            return e ? SnH[j] : 0ull;
        };
        auto nlEnt = [&](uint32_t j, bool& e) -> ull {
            e = (j & (BPB - 1u)) < bc[(j >> LOGB) * 4 + 2];
            return e ? SnL[j] : 0ull;
        };
        auto igEnt = [&](uint32_t j, bool& e) -> ull {
            e = (j & (BPB - 1u)) < bc[(j >> LOGB) * 4 + 3];
            return e ? Sign[j] : 0ull;
        };
        auto radix = [&](auto&& kf, uint32_t m, uint32_t k, int shift) -> ull {
            if (m <= GCAP) {   // direct: gather all eligible, rank-select
                if (tid == 0) gcnt = 0;
                __syncthreads();
                for (uint32_t j = tid; j < m; j += 1024) {
                    bool e; ull key = kf(j, e);
                    if (e) { uint32_t s = atomicAdd(&gcnt, 1u); gatA[s] = key; }
                }
                __syncthreads();
                uint32_t gc = gcnt;
                if ((uint32_t)tid < gc) {
                    ull x = gatA[tid]; uint32_t r = 0;
                    for (uint32_t j = 0; j < gc; j++) r += (gatA[j] > x);
                    if (r == k - 1) sh_thr = x;
                }
                __syncthreads();
                return sh_thr;
            }
            ull prefix = 0, mask = 0;
            for (;;) {
                histA[tid] = 0; histA[tid + 1024] = 0;
                __syncthreads();
                for (uint32_t j = tid; j < m; j += 1024) {
                    bool e; ull key = kf(j, e);
                    if (e && ((key ^ prefix) & mask) == 0)
                        atomicAdd(&histA[(uint32_t)(key >> shift) & 2047u], 1u);
                }
                __syncthreads();
                if (tid < 64) locW(histA, k, shS);
                __syncthreads();
                uint32_t dig = shS[0], kk = shS[1], cnt = shS[2];
                prefix |= ((ull)dig) << shift;
                mask   |= 2047ull << shift;
                if (cnt <= GCAP || shift == 0) {
                    if (tid == 0) gcnt = 0;
                    __syncthreads();
                    for (uint32_t j = tid; j < m; j += 1024) {
                        bool e; ull key = kf(j, e);
                        if (e && ((key ^ prefix) & mask) == 0) {
                            uint32_t s = atomicAdd(&gcnt, 1u);
                            if (s < GCAP) gatA[s] = key;
                        }
                    }
                    __syncthreads();
                    uint32_t gc = (gcnt < GCAP) ? gcnt : GCAP;
                    if ((uint32_t)tid < gc) {
                        ull x = gatA[tid]; uint32_t r = 0;
                        for (uint32_t j = 0; j < gc; j++) r += (gatA[j] > x);
                        if (r == kk - 1) sh_thr = x;
                    }
                    __syncthreads();
                    return sh_thr;
                } else {
                    k = kk;
                    shift = (shift >= 11) ? shift - 11 : 0;
                    __syncthreads();
                }
            }
        };

        // phase 0: thrA = 64th-largest keyA among positives (only if npos > 64)
        if (npos > NFG) {
            thrA = radix([&](uint32_t j, bool& e) -> ull {
                ull ent = posEnt(j, e); return keyA_of(ent); }, mPos, NFG, 26);
        }
        // phase 1: boundary class analytic
        uint32_t clsStar = (npn >= NSAMP) ? ((NSAMP <= c3 + nneg) ? 2u : 1u) : 0u;
        bool scanL = true;
        ull thrB = 0;
        if (clsStar == 2u) {
            if (nH >= k2) {     // top negatives all in the high slab
                scanL = false;  // negL keys provably < any negH key (strict NEGT sep)
                thrB = radix([&](uint32_t j, bool& e) -> ull {
                    ull ent = nhEnt(j, e); return keyB_neg(ent); }, mH, k2, 26);
            } else {            // virtual concat negH ++ negL (masked segmented)
                thrB = radix([&](uint32_t j, bool& e) -> ull {
                    if (j < mH) { ull ent = nhEnt(j, e); return keyB_neg(ent); }
                    ull ent = nlEnt(j - mH, e); return keyB_neg(ent); },
                    mH + MSEG, k2, 26);
            }
        } else if (clsStar == 1u) {
            thrB = radix([&](uint32_t j, bool& e) -> ull {
                ull ent = posEnt(j, e);
                ull kb = keyB_pos(ent);
                e = e && ((kb >> 14) < 0x40000000ull);   // cls1 only (prio < 2.0)
                return kb; }, mPos, NSAMP - c3 - nneg, 26);
        } else {
            thrB = radix([&](uint32_t j, bool& e) -> ull {
                ull ent = igEnt(j, e); return keyB_ign(ent); }, MSEG, NSAMP - npn, 34);
        }
        __syncthreads();
        // compact
        for (uint32_t j = tid; j < mPos; j += 1024) {
            bool e; ull ent = posEnt(j, e);
            if (!e) continue;
            ull key = keyB_pos(ent);
            if (clsStar == 0u || key >= thrB) push(key, ent, 1u);
        }
        for (uint32_t j = tid; j < mH; j += 1024) {
            bool e; ull ent = nhEnt(j, e);
            if (!e) continue;
            ull key = keyB_neg(ent);
            if (clsStar == 0u || key >= thrB) push(key, ent, 0u);
        }
        if (scanL) {
            for (uint32_t j = tid; j < MSEG; j += 1024) {
                bool e; ull ent = nlEnt(j, e);
                if (!e) continue;
                ull key = keyB_neg(ent);
                if (clsStar == 0u || key >= thrB) push(key, ent, 0u);
            }
        }
        if (clsStar == 0u) {
            for (uint32_t j = tid; j < MSEG; j += 1024) {
                bool e; ull ent = igEnt(j, e);
                if (!e) continue;
                ull key = keyB_ign(ent);
                if (key >= thrB) push(key, ent, 0u);
            }
        }
        __syncthreads();
    }

    // ---- S7: rank-scatter: output row = count of greater keys (desc sort position)
    if (tid < NSAMP) {
        ull x = selk[tid];
        uint32_t r = 0;
        for (int j = 0; j < NSAMP; j++) r += (selk[j] > x);
        uint32_t n = 16383u - (uint32_t)(x & 0x3FFFull);
        uint32_t aux = sela[tid];
        uint32_t bg = aux & 0x7Fu;
        const int isfg = (int)((aux >> 7) & 1u);
        const float4 pb = ((const float4*)props)[(size_t)b * NPROP + n];
        const float4 gb = ((const float4*)gts)[(size_t)b * NGT + bg];
        const size_t O_ROI = 0;
        const size_t O_LBL = (size_t)BATCH * NSAMP * 4;
        const size_t O_TGT = O_LBL + (size_t)BATCH * NSAMP;
        const size_t O_INW = O_TGT + (size_t)BATCH * NSAMP * 4;
        const size_t O_OUW = O_INW + (size_t)BATCH * NSAMP * 4;
        const size_t row = (size_t)b * NSAMP + r;
        out[O_ROI + row * 4 + 0] = pb.x;
        out[O_ROI + row * 4 + 1] = pb.y;
        out[O_ROI + row * 4 + 2] = pb.z;
        out[O_ROI + row * 4 + 3] = pb.w;
        out[O_LBL + row] = isfg ? 1.0f : 0.0f;
        float rw  = pb.z - pb.x, rh = pb.w - pb.y;
        float gw  = gb.z - gb.x, gh = gb.w - gb.y;
        out[O_TGT + row * 4 + 0] = ((gb.x + gb.z) * 0.5f - (pb.x + pb.z) * 0.5f) / rw;
        out[O_TGT + row * 4 + 1] = ((gb.y + gb.w) * 0.5f - (pb.y + pb.w) * 0.5f) / rh;
        out[O_TGT + row * 4 + 2] = logf(gw / rw);
        out[O_TGT + row * 4 + 3] = logf(gh / rh);
        float wv = isfg ? 1.0f : 0.0f;
        for (int c = 0; c < 4; c++) {
            out[O_INW + row * 4 + c] = wv;
            out[O_OUW + row * 4 + c] = wv;
        }
    }
}

extern "C" void kernel_launch(void* const* d_in, const int* in_sizes, int n_in,
                              void* d_out, int out_size, void* d_ws, size_t ws_size,
                              hipStream_t stream) {
    (void)in_sizes; (void)n_in; (void)out_size; (void)ws_size;
    const float* props = (const float*)d_in[0];
    const float* gts   = (const float*)d_in[1];
    ull* lists = (ull*)d_ws;                                       // 16*4*16384*8 = 8 MB
    uint32_t* cntblk = (uint32_t*)((char*)d_ws + (size_t)BATCH * 4 * NPROP * 8); // 16 KB
    float* out = (float*)d_out;

    dim3 gridA(NBLK, BATCH);   // (64, 16), 256 threads: 1 proposal/lane
    k_compute<<<gridA, 256, 0, stream>>>(props, gts, lists, cntblk);
    k_select<<<BATCH, 1024, 0, stream>>>(props, gts, lists, cntblk, out);
}